// Round 10
// baseline (429.941 us; speedup 1.0000x reference)
//
#include <hip/hip_runtime.h>
#include <hip/hip_fp16.h>
#include <math.h>

// ---------------------------------------------------------------------------
// Net_75505525064500 — round 19 (Y-factored level-2 in REGISTERS, wave/dst).
// Ledger of failed approaches (do NOT retry):
//   R12 cluster-granularity serial fusion: parallelism collapse, 154 us.
//   R13 looped wave-per-node msg2 with 32 LDS b128/edge in the loop: 160 us.
//   R14 LDS-atomic Y-bins: f32 LDS atomic collision storm, 508 us.
//   R15 edge2m relayout (random-k b128 rows: no static bank fix; ~7.5M
//     conflict cycles = floor); ILP4 hist (atomic-return wall ~23 G/s).
//   R17 node2R: 3-deep indirection loop, 149 us. RULE: looped waves get at
//     most ONE indirection and NO heavy LDS inside the loop.
// R18 best: 347.9 us. edge2m's 2.6 GB LDS read floor (~45 us) is structural
//   per-edge; only factorization removes it.
// R19:
//   edge2Y (replaces edge2m+reduce2): wave per dst; per edge TWO 16-B
//     broadcast loads (rec4 meta, x1chU) + ~15 predicated VALU/lane
//     (lane owns k=lane>>1, channels (lane&1)*4..+3; valid iff
//     k-ibase in {0,1,3,4,9,10,12,13} = mask 13851). Y[216] f32 written
//     once to wave-private LDS slot (no atomics); contraction vs W2t
//     (stride 217, <=2-way banks) -> M2n[d,16] full f32. Kills msg2h
//     82 MB round-trip + the 2.6 GB LDS floor.
//   comb2: per (c1,o) sums ~2 member M2n / total deg -> M2.
//   node2f: thread per (c2,o) — 16x the old node2 parallelism.
// Chain: memset -> hist -> scan_one -> scatB -> reduce1 -> node1 ->
//        edge2Y -> comb2 -> node2f -> head.
// Sizes: N=80000 (Cin=2), E=1280000, N1=40000 (C=8), N2=20000 (C=16), B=16.
// ---------------------------------------------------------------------------

__device__ __forceinline__ float eluf(float x) {
    return x > 0.f ? x : (expf(x) - 1.f);
}

__device__ __forceinline__ float hlo(int v) {
    __half2 h; *(int*)&h = v; return __low2float(h);
}
__device__ __forceinline__ float hhi(int v) {
    __half2 h; *(int*)&h = v; return __high2float(h);
}

__device__ __forceinline__ float hlou(unsigned v) {
    __half2 h; *(unsigned*)&h = v; return __low2float(h);
}
__device__ __forceinline__ float hhiu(unsigned v) {
    __half2 h; *(unsigned*)&h = v; return __high2float(h);
}

#define W1_STRIDE 20
#define W2T_STRIDE 217   // [o][kc] stride: 217 mod 32 = 25 (odd) -> the 16
                         // o-lanes hit distinct banks; cross-q overlaps <=2-way

// rec per edge (2 x int4 = 32 B, one sector):
//   [0].x = s2 | ibase<<16    (s2 < 65536, ibase < 27)
//   [0].y = half(fx) | half(fy)<<16
//   [0].z = half(fz)
//   [0].w = d (dst node id)
//   [1]   = msg1 as 8 halves (ch pairs 01,23,45,67)

// ---- phase 1: histograms + within-bin ranks (atomic-return throughput
//      wall ~23 G/s — structural floor, R11-proven). ----
__global__ __launch_bounds__(256) void hist_kernel(
    const int* __restrict__ ei, const int* __restrict__ cluster1,
    const int* __restrict__ cluster2,
    int* __restrict__ deg, int* __restrict__ rank,
    int* __restrict__ cdeg, int* __restrict__ rankC,
    int* __restrict__ c2deg, int* __restrict__ rank2,
    int E, int N, int N1)
{
    int i = blockIdx.x * 256 + threadIdx.x;
    if (i < E)  rank[i]  = atomicAdd(&deg[ei[E + i]], 1);
    if (i < N)  rankC[i] = atomicAdd(&cdeg[cluster1[i]], 1);
    if (i < N1) rank2[i] = atomicAdd(&c2deg[cluster2[i]], 1);
}

// ---- phase 2: single-pass exclusive scan, 3 arrays in one launch. ----
#define SCAN_CHUNK 4096

__global__ __launch_bounds__(256) void scan_one(
    const int* __restrict__ in0, int* __restrict__ out0, int* __restrict__ st0, int L0, int nb0,
    const int* __restrict__ in1, int* __restrict__ out1, int* __restrict__ st1, int L1, int nb1,
    const int* __restrict__ in2, int* __restrict__ out2, int* __restrict__ st2, int L2)
{
    int b = blockIdx.x;
    const int* in; int* out; int* st; int L;
    if (b < nb0)            { in = in0; out = out0; st = st0; L = L0; }
    else if (b < nb0 + nb1) { b -= nb0; in = in1; out = out1; st = st1; L = L1; }
    else                    { b -= nb0 + nb1; in = in2; out = out2; st = st2; L = L2; }
    int nb = (L + SCAN_CHUNK - 1) / SCAN_CHUNK;

    __shared__ int ls[256];
    __shared__ int pre[32];
    __shared__ int blkExcl;
    int t = threadIdx.x;
    int base = b * SCAN_CHUNK + t * 16;
    int v[16];
    int s = 0;
#pragma unroll
    for (int j = 0; j < 16; ++j) {
        int val = (base + j < L) ? in[base + j] : 0;
        v[j] = s;
        s += val;
    }
    ls[t] = s;
    __syncthreads();
    for (int off = 1; off < 256; off <<= 1) {
        int tv = (t >= off) ? ls[t - off] : 0;
        __syncthreads();
        ls[t] += tv;
        __syncthreads();
    }
    int excl = ls[t] - s;
    int total = ls[255];
    if (t == 255) {
        __threadfence();
        atomicExch(&st[b], total + 1);   // publish early (before lookback)
    }
    if (t < b) {                          // b <= 19 < 32
        int val;
        do { val = atomicAdd(&st[t], 0); } while (val == 0);
        pre[t] = val - 1;
    }
    __syncthreads();
    if (t == 0) {
        int r = 0;
        for (int j = 0; j < b; ++j) r += pre[j];
        blkExcl = r;
    }
    __syncthreads();
    int be = blkExcl;
#pragma unroll
    for (int j = 0; j < 16; ++j)
        if (base + j < L) out[base + j] = be + excl + v[j];
    if (b == nb - 1 && t == 255) out[L] = be + total;
}

// ---- phase 3 (fused): CSR scatter + level-1 message compute. ----
__global__ __launch_bounds__(256) void scatB_kernel(
    const int* __restrict__ ei, const float* __restrict__ attr,
    const int* __restrict__ cluster1, const int* __restrict__ cluster2,
    const float2* __restrict__ x, const float* __restrict__ W1,
    const int* __restrict__ doffs, const int* __restrict__ rank,
    const int* __restrict__ coff, const int* __restrict__ rankC,
    const int* __restrict__ c2off, const int* __restrict__ rank2,
    int* __restrict__ nidx, int* __restrict__ n1idx,
    int4* __restrict__ rec4, int E, int N, int N1)
{
    __shared__ float lw[27 * W1_STRIDE];
    for (int i = threadIdx.x; i < 27 * 16; i += 256)
        lw[(i >> 4) * W1_STRIDE + (i & 15)] = W1[i];
    __syncthreads();

    int i = blockIdx.x * 256 + threadIdx.x;
    if (i < E) {
        int s = ei[i], d = ei[E + i];
        int p = doffs[d] + rank[i];

        float vx = attr[3 * i] * 2.f, vy = attr[3 * i + 1] * 2.f, vz = attr[3 * i + 2] * 2.f;
        float ix = fmaxf(fminf(floorf(vx), 1.f), 0.f);
        float iy = fmaxf(fminf(floorf(vy), 1.f), 0.f);
        float iz = fmaxf(fminf(floorf(vz), 1.f), 0.f);
        float fx = vx - ix, fy = vy - iy, fz = vz - iz;
        int ibase = (int)ix + 3 * (int)iy + 9 * (int)iz;

        float2 xv = x[s];  // 640 KB, L2-resident random read
        float wxv[2] = {1.f - fx, fx}, wyv[2] = {1.f - fy, fy}, wzv[2] = {1.f - fz, fz};
        float m[8];
#pragma unroll
        for (int o = 0; o < 8; ++o) m[o] = 0.f;
#pragma unroll
        for (int j = 0; j < 8; ++j) {
            int cx = j & 1, cy = (j >> 1) & 1, cz = j >> 2;
            float w = wxv[cx] * wyv[cy] * wzv[cz];
            const float* Wk = &lw[(ibase + cx + 3 * cy + 9 * cz) * W1_STRIDE];
            float a = w * xv.x, bb = w * xv.y;
            const float4 wa0 = *(const float4*)&Wk[0];
            const float4 wa1 = *(const float4*)&Wk[4];
            const float4 wb0 = *(const float4*)&Wk[8];
            const float4 wb1 = *(const float4*)&Wk[12];
            m[0] += a * wa0.x + bb * wb0.x;
            m[1] += a * wa0.y + bb * wb0.y;
            m[2] += a * wa0.z + bb * wb0.z;
            m[3] += a * wa0.w + bb * wb0.w;
            m[4] += a * wa1.x + bb * wb1.x;
            m[5] += a * wa1.y + bb * wb1.y;
            m[6] += a * wa1.z + bb * wb1.z;
            m[7] += a * wa1.w + bb * wb1.w;
        }

        unsigned hfx = __half_as_ushort(__float2half_rn(fx));
        unsigned hfy = __half_as_ushort(__float2half_rn(fy));
        unsigned hfz = __half_as_ushort(__float2half_rn(fz));
        int s2 = cluster1[s];
        int4 ra = make_int4(s2 | (ibase << 16),
                            (int)(hfx | (hfy << 16)), (int)hfz, d);
        __half2 h01 = __floats2half2_rn(m[0], m[1]);
        __half2 h23 = __floats2half2_rn(m[2], m[3]);
        __half2 h45 = __floats2half2_rn(m[4], m[5]);
        __half2 h67 = __floats2half2_rn(m[6], m[7]);
        int4 rb = make_int4(*(int*)&h01, *(int*)&h23, *(int*)&h45, *(int*)&h67);
        rec4[2 * (size_t)p]     = ra;
        rec4[2 * (size_t)p + 1] = rb;
    }
    if (i < N)  nidx[coff[cluster1[i]] + rankC[i]] = i;
    if (i < N1) n1idx[c2off[cluster2[i]] + rank2[i]] = i;
}

// ---- level-1 reduce: WAVE per node (8 ch x 8 edge-slots). ----
__global__ __launch_bounds__(256) void reduce1_kernel(
    const int* __restrict__ doffs, const unsigned short* __restrict__ recU,
    float* __restrict__ M1, int N)
{
    int lane = threadIdx.x & 63;
    int ch = lane & 7, q = lane >> 3;
    int d = (blockIdx.x << 2) + (threadIdx.x >> 6);
    if (d >= N) return;
    int beg = doffs[d], end = doffs[d + 1];
    float acc = 0.f;
    for (int p = beg + q; p < end; p += 8)
        acc += __half2float(__ushort_as_half(recU[(size_t)p * 16 + 8 + ch]));
    acc += __shfl_xor(acc, 8);
    acc += __shfl_xor(acc, 16);
    acc += __shfl_xor(acc, 32);
    if (q == 0)
        M1[(size_t)d * 8 + ch] = acc / fmaxf((float)(end - beg), 1.f);
}

// ---- level 1 pool: per (cluster, ch); emits x1c (f32) + x1ch (half) ----
__global__ __launch_bounds__(256) void node1_kernel(
    const int* __restrict__ coff, const int* __restrict__ nidx,
    const float* __restrict__ M1, const float2* __restrict__ x,
    const float* __restrict__ root1, const float* __restrict__ b1,
    const int* __restrict__ batch,
    float* __restrict__ x1c, unsigned short* __restrict__ x1chU,
    int* __restrict__ batch1, int N1)
{
    int t = blockIdx.x * 256 + threadIdx.x;
    if (t >= N1 * 8) return;
    int c = t >> 3, ch = t & 7;
    int cb = coff[c], ce = coff[c + 1];
    float r0 = root1[ch], r1 = root1[8 + ch], bo = b1[ch];
    float hm = -INFINITY;
    int bm = 0;
    for (int idx = cb; idx < ce; ++idx) {
        int d = nidx[idx];
        float2 xv = x[d];
        float h = eluf(M1[d * 8 + ch] + xv.x * r0 + xv.y * r1 + bo);
        hm = fmaxf(hm, h);
        bm = max(bm, batch[d]);
    }
    if (ce == cb) hm = 0.f;  // empty cluster -> 0 (ref isfinite mask)
    x1c[t] = hm;
    x1chU[t] = __half_as_ushort(__float2half_rn(hm));
    if (ch == 0) batch1[c] = bm;
}

// ---- level-2 Y-factored messages: WAVE per dst. Per edge: two 16-B
//      BROADCAST loads + ~15 predicated VALU/lane (lane owns k=lane>>1,
//      4 channels). Y (216 f32) accumulated in registers, written once
//      to a wave-private LDS slot (no atomics), then contracted against
//      W2t -> M2n[d][16] in full f32. Replaces edge2m+reduce2. ----
__global__ __launch_bounds__(256) void edge2Y_kernel(
    const int* __restrict__ doffs, const int4* __restrict__ rec4,
    const unsigned short* __restrict__ x1chU, const float* __restrict__ W2,
    float* __restrict__ M2n, int N)
{
    __shared__ float w2t[16 * W2T_STRIDE];   // [o][kc], kc = k*8+c
    __shared__ float Y[4 * 256];             // per-wave slot, 216 used
    int tid = threadIdx.x;
    for (int j = tid; j < 27 * 8 * 16; j += 256) {
        int o = j & 15, kc = j >> 4;
        w2t[o * W2T_STRIDE + kc] = W2[j];
    }
    int wid = tid >> 6, lane = tid & 63;
    int d = (blockIdx.x << 2) + wid;
    float* Yw = &Y[wid * 256];

    int myk = lane >> 1;            // 0..31 (>=27 always masked out)
    int csel = lane & 1;            // 0: ch 0-3, 1: ch 4-7
    float y0 = 0.f, y1 = 0.f, y2 = 0.f, y3 = 0.f;
    if (d < N) {
        int beg = doffs[d], end = doffs[d + 1];
        for (int p = beg; p < end; ++p) {
            int4 ra = rec4[2 * (size_t)p];          // 16-B broadcast
            int s2 = ra.x & 0xFFFF;
            int ibase = (ra.x >> 16) & 31;
            float fx = hlo(ra.y), fy = hhi(ra.y), fz = hlo(ra.z);
            const uint4 xv4 = *(const uint4*)&x1chU[(size_t)s2 * 8];  // broadcast
            unsigned lo_ = csel ? xv4.z : xv4.x;
            unsigned hi_ = csel ? xv4.w : xv4.y;
            float xa = hlou(lo_), xb = hhiu(lo_);
            float xc = hlou(hi_), xd = hhiu(hi_);
            int tt = myk - ibase;
            float w = 0.f;
            if (tt >= 0 && tt <= 13 && ((13851 >> tt) & 1)) {
                int dxm = tt % 3;
                int rem = tt / 3;
                int dym = rem % 3;
                int dzm = rem / 3;
                float wx = dxm ? fx : 1.f - fx;
                float wy = dym ? fy : 1.f - fy;
                float wz = dzm ? fz : 1.f - fz;
                w = wx * wy * wz;
            }
            y0 = fmaf(w, xa, y0);
            y1 = fmaf(w, xb, y1);
            y2 = fmaf(w, xc, y2);
            y3 = fmaf(w, xd, y3);
        }
    }
    // lane's components kc = myk*8 + csel*4 + j  == lane*4 + j
    *(float4*)&Yw[lane * 4] = make_float4(y0, y1, y2, y3);
    __syncthreads();

    if (d < N) {
        int o = lane & 15, q = lane >> 4;
        const float* wrow = &w2t[o * W2T_STRIDE];
        float acc = 0.f;
#pragma unroll 6
        for (int i = 0; i < 54; ++i) {
            int kc = 4 * i + q;                      // <= 215
            acc = fmaf(wrow[kc], Yw[kc], acc);
        }
        acc += __shfl_xor(acc, 16);
        acc += __shfl_xor(acc, 32);
        if (q == 0) M2n[(size_t)d * 16 + o] = acc;   // SUM over dst's edges
    }
}

// ---- level-2 combine: per (c1 cluster, o) sums ~2 member-node M2n ----
__global__ __launch_bounds__(256) void comb2_kernel(
    const int* __restrict__ coff, const int* __restrict__ nidx,
    const int* __restrict__ doffs, const float* __restrict__ M2n,
    float* __restrict__ M2, int N1)
{
    int t = blockIdx.x * 256 + threadIdx.x;
    if (t >= N1 * 16) return;
    int c = t >> 4, o = t & 15;
    int cb = coff[c], ce = coff[c + 1];
    float acc = 0.f;
    int cnt = 0;
    for (int idx = cb; idx < ce; ++idx) {
        int d = nidx[idx];
        acc += M2n[(size_t)d * 16 + o];
        cnt += doffs[d + 1] - doffs[d];
    }
    M2[t] = acc / fmaxf((float)cnt, 1.f);
}

// ---- level 2 node + pool + graph sum: thread per (c2, o) — 16x the
//      parallelism of the old thread-per-c2 form (which was 312 waves
//      device-wide, latency-starved). ----
__global__ __launch_bounds__(256) void node2f_kernel(
    const int* __restrict__ c2off, const int* __restrict__ n1idx,
    const float* __restrict__ M2, const float* __restrict__ x1c,
    const float* __restrict__ root2, const float* __restrict__ b2,
    const int* __restrict__ batch1,
    float* __restrict__ gsum, float* __restrict__ gcnt, int N2)
{
    __shared__ float ls[16 * 16];
    __shared__ float lc[16];
    __shared__ float r2[128];
    for (int i = threadIdx.x; i < 256; i += 256) ls[i] = 0.f;
    if (threadIdx.x < 16) lc[threadIdx.x] = 0.f;
    if (threadIdx.x < 128) r2[threadIdx.x] = root2[threadIdx.x];
    __syncthreads();

    int t = blockIdx.x * 256 + threadIdx.x;
    if (t < N2 * 16) {
        int c2 = t >> 4, o = t & 15;
        int cb = c2off[c2], ce = c2off[c2 + 1];
        float bo = b2[o];
        float hm = -INFINITY;
        int bm = 0;
        for (int idx = cb; idx < ce; ++idx) {
            int n1 = n1idx[idx];
            const float4* xr4 = (const float4*)&x1c[(size_t)n1 * 8];
            float4 xa = xr4[0], xb = xr4[1];
            float v = M2[(size_t)n1 * 16 + o] + bo
                    + xa.x * r2[o] + xa.y * r2[16 + o]
                    + xa.z * r2[32 + o] + xa.w * r2[48 + o]
                    + xb.x * r2[64 + o] + xb.y * r2[80 + o]
                    + xb.z * r2[96 + o] + xb.w * r2[112 + o];
            hm = fmaxf(hm, eluf(v));
            bm = max(bm, batch1[n1]);
        }
        if (ce == cb) hm = 0.f;
        atomicAdd(&ls[bm * 16 + o], hm);
        if (o == 0) atomicAdd(&lc[bm], 1.f);
    }
    __syncthreads();
    for (int i = threadIdx.x; i < 256; i += 256) unsafeAtomicAdd(&gsum[i], ls[i]);
    if (threadIdx.x < 16) unsafeAtomicAdd(&gcnt[threadIdx.x], lc[threadIdx.x]);
}

// ---- head ----
__global__ __launch_bounds__(256) void head_kernel(
    const float* __restrict__ gsum, const float* __restrict__ gcnt,
    const float* __restrict__ fc1_w, const float* __restrict__ fc1_b,
    const float* __restrict__ fc2_w, const float* __restrict__ fc2_b,
    float* __restrict__ out, int B)
{
    __shared__ float g[16 * 16];
    __shared__ float h1[16 * 64];
    int t = threadIdx.x;
    if (t < B * 16) {
        int b = t >> 4;
        g[t] = gsum[t] / fmaxf(gcnt[b], 1.f);
    }
    __syncthreads();
    for (int j = t; j < B * 64; j += 256) {
        int b = j >> 6, jj = j & 63;
        float s = fc1_b[jj];
#pragma unroll
        for (int c = 0; c < 16; ++c) s += g[b * 16 + c] * fc1_w[c * 64 + jj];
        h1[j] = eluf(s);
    }
    __syncthreads();
    if (t < B) {
        float s = fc2_b[0];
#pragma unroll
        for (int j = 0; j < 64; ++j) s += h1[t * 64 + j] * fc2_w[j];
        out[t] = eluf(s);
    }
}

extern "C" void kernel_launch(void* const* d_in, const int* in_sizes, int n_in,
                              void* d_out, int out_size, void* d_ws, size_t ws_size,
                              hipStream_t stream)
{
    const float* x        = (const float*)d_in[0];
    const int*   ei       = (const int*)  d_in[1];
    const float* attr     = (const float*)d_in[2];
    const int*   batch    = (const int*)  d_in[3];
    const int*   cluster1 = (const int*)  d_in[4];
    const int*   cluster2 = (const int*)  d_in[5];
    const float* W1       = (const float*)d_in[6];
    const float* root1    = (const float*)d_in[7];
    const float* b1       = (const float*)d_in[8];
    const float* W2       = (const float*)d_in[9];
    const float* root2    = (const float*)d_in[10];
    const float* b2       = (const float*)d_in[11];
    const float* fc1_w    = (const float*)d_in[12];
    const float* fc1_b    = (const float*)d_in[13];
    const float* fc2_w    = (const float*)d_in[14];
    const float* fc2_b    = (const float*)d_in[15];

    const int N  = in_sizes[0] / 2;
    const int E  = in_sizes[1] / 2;
    const int N1 = in_sizes[5];
    const int N2 = N1 / 2;
    const int B  = out_size;

    const int nb0 = (N  + SCAN_CHUNK - 1) / SCAN_CHUNK;
    const int nb1 = (N1 + SCAN_CHUNK - 1) / SCAN_CHUNK;
    const int nb2 = (N2 + SCAN_CHUNK - 1) / SCAN_CHUNK;

    int* wi = (int*)d_ws;
    size_t off = 0;
    auto alloc = [&](size_t n, size_t align = 1) {
        off = (off + align - 1) & ~(align - 1);
        size_t r = off; off += n; return r;
    };
    // zero-init region
    int*   deg    = wi + alloc(N);
    int*   cdeg   = wi + alloc(N1);
    int*   c2deg  = wi + alloc(N2);
    float* gsum   = (float*)(wi + alloc((size_t)B * 16));
    float* gcnt   = (float*)(wi + alloc(B));
    int*   st0    = wi + alloc(32);
    int*   st1    = wi + alloc(32);
    int*   st2    = wi + alloc(32);
    const size_t zcount = off;
    // rest (fully overwritten before read)
    int*   doffs  = wi + alloc(N + 1);
    int*   coff   = wi + alloc(N1 + 1);
    int*   c2off  = wi + alloc(N2 + 1);
    int*   rank   = wi + alloc(E);
    int*   rankC  = wi + alloc(N);
    int*   rank2  = wi + alloc(N1);
    int*   nidx   = wi + alloc(N);
    int*   n1idx  = wi + alloc(N1);
    int4*  rec4   = (int4*)(wi + alloc((size_t)E * 8, 8));   // 32-B records
    float* M1     = (float*)(wi + alloc((size_t)N * 8, 4));
    float* M2n    = (float*)(wi + alloc((size_t)N * 16, 4)); // fully written
    float* x1c    = (float*)(wi + alloc((size_t)N1 * 8, 4));
    unsigned short* x1chU = (unsigned short*)(wi + alloc((size_t)N1 * 4, 4));
    int*   batch1 = wi + alloc(N1);
    float* M2     = (float*)(wi + alloc((size_t)N1 * 16, 4));
    (void)ws_size;  // peak ~60 MB (msg2h eliminated)

    hipMemsetAsync(d_ws, 0, zcount * sizeof(int), stream);

    const int eb = (E + 255) / 256;
    hist_kernel<<<eb, 256, 0, stream>>>(ei, cluster1, cluster2,
                                        deg, rank, cdeg, rankC, c2deg, rank2, E, N, N1);
    scan_one<<<nb0 + nb1 + nb2, 256, 0, stream>>>(deg, doffs, st0, N, nb0,
                                                  cdeg, coff, st1, N1, nb1,
                                                  c2deg, c2off, st2, N2);
    scatB_kernel<<<eb, 256, 0, stream>>>(ei, attr, cluster1, cluster2,
                                         (const float2*)x, W1,
                                         doffs, rank, coff, rankC, c2off, rank2,
                                         nidx, n1idx, rec4, E, N, N1);
    reduce1_kernel<<<(N + 3) / 4, 256, 0, stream>>>(
        doffs, (const unsigned short*)rec4, M1, N);
    node1_kernel<<<(N1 * 8 + 255) / 256, 256, 0, stream>>>(
        coff, nidx, M1, (const float2*)x, root1, b1, batch,
        x1c, x1chU, batch1, N1);
    edge2Y_kernel<<<(N + 3) / 4, 256, 0, stream>>>(
        doffs, rec4, x1chU, W2, M2n, N);
    comb2_kernel<<<(N1 * 16 + 255) / 256, 256, 0, stream>>>(
        coff, nidx, doffs, M2n, M2, N1);
    node2f_kernel<<<(N2 * 16 + 255) / 256, 256, 0, stream>>>(
        c2off, n1idx, M2, x1c, root2, b2, batch1, gsum, gcnt, N2);
    head_kernel<<<1, 256, 0, stream>>>(gsum, gcnt, fc1_w, fc1_b, fc2_w, fc2_b,
                                       (float*)d_out, B);
}

// Round 11
// 373.335 us; speedup vs baseline: 1.1516x; 1.1516x over previous
//
#include <hip/hip_runtime.h>
#include <hip/hip_fp16.h>
#include <math.h>

// ---------------------------------------------------------------------------
// Net_75505525064500 — round 20 (R18 base + atomic-wall experiment).
// Ledger of failed approaches (do NOT retry):
//   R12 cluster-granularity serial fusion: parallelism collapse, 154 us.
//   R13 looped wave-per-node msg2 (LDS in loop): 160 us.
//   R14 LDS-atomic Y-bins: collision storm, 508 us.
//   R15 edge2m relayout: random-k b128 rows have no static bank fix.
//   R17 node2R: 3-deep indirection loop, 149 us.
//   R19 edge2Y register-factorization: serial per-edge wave loop, all-lane
//     predicated weights = 2x VALU, 167 us. Level-2 factorization is 0/3;
//     edge-parallel one-shot edge2m is the proven shape.
// R18 best: 347.9 us (hist 58 / scatB ~55 / edge2m 58.8 floors).
// R20 experiment — split the atomic wall:
//   hist: deg counting only, NON-RETURNING atomicAdd. If the 23 G/s wall
//     is the return path, hist -> ~20 us; if unit throughput, stays ~55.
//   scatB: rank via cursor atomics (doffs[d] + atomicAdd(&cur[d],1)),
//     issued early so the ~56 us of atomic-unit time overlaps the ~55 us
//     of spline compute. rank/rankC/rank2 arrays deleted (-10 MB traffic).
// Chain: memset -> hist -> scan_one -> scatB -> reduce1 -> node1 ->
//        edge2m -> reduce2 -> node2 -> head.
// Sizes: N=80000 (Cin=2), E=1280000, N1=40000 (C=8), N2=20000 (C=16), B=16.
// ---------------------------------------------------------------------------

__device__ __forceinline__ float eluf(float x) {
    return x > 0.f ? x : (expf(x) - 1.f);
}

__device__ __forceinline__ float hlo(int v) {
    __half2 h; *(int*)&h = v; return __low2float(h);
}
__device__ __forceinline__ float hhi(int v) {
    __half2 h; *(int*)&h = v; return __high2float(h);
}

typedef _Float16 half2v __attribute__((ext_vector_type(2)));

__device__ __forceinline__ half2v uash2(unsigned u) {
    half2v h; *(unsigned*)&h = u; return h;
}

__device__ __forceinline__ float dot2f(half2v a, half2v b, float c) {
#if __has_builtin(__builtin_amdgcn_fdot2)
    return __builtin_amdgcn_fdot2(a, b, c, false);
#else
    return c + (float)a[0] * (float)b[0] + (float)a[1] * (float)b[1];
#endif
}

#define W1_STRIDE 20
#define W2H_STRIDE 68  // dwords per k-row: 64 payload (16 o x 4 half2) + 4 pad

// rec per edge (2 x int4 = 32 B, one sector):
//   [0].x = s2 | ibase<<16    (s2 < 65536, ibase < 27)
//   [0].y = half(fx) | half(fy)<<16
//   [0].z = half(fz)
//   [0].w = d (dst node id; spare)
//   [1]   = msg1 as 8 halves (ch pairs 01,23,45,67)

// ---- phase 1: degree histograms ONLY, non-returning atomics. ----
__global__ __launch_bounds__(256) void hist_kernel(
    const int* __restrict__ ei, const int* __restrict__ cluster1,
    const int* __restrict__ cluster2,
    int* __restrict__ deg, int* __restrict__ cdeg, int* __restrict__ c2deg,
    int E, int N, int N1)
{
    int i = blockIdx.x * 256 + threadIdx.x;
    if (i < E)  atomicAdd(&deg[ei[E + i]], 1);     // result unused -> no return
    if (i < N)  atomicAdd(&cdeg[cluster1[i]], 1);
    if (i < N1) atomicAdd(&c2deg[cluster2[i]], 1);
}

// ---- phase 2: single-pass exclusive scan, 3 arrays in one launch. ----
#define SCAN_CHUNK 4096

__global__ __launch_bounds__(256) void scan_one(
    const int* __restrict__ in0, int* __restrict__ out0, int* __restrict__ st0, int L0, int nb0,
    const int* __restrict__ in1, int* __restrict__ out1, int* __restrict__ st1, int L1, int nb1,
    const int* __restrict__ in2, int* __restrict__ out2, int* __restrict__ st2, int L2)
{
    int b = blockIdx.x;
    const int* in; int* out; int* st; int L;
    if (b < nb0)            { in = in0; out = out0; st = st0; L = L0; }
    else if (b < nb0 + nb1) { b -= nb0; in = in1; out = out1; st = st1; L = L1; }
    else                    { b -= nb0 + nb1; in = in2; out = out2; st = st2; L = L2; }
    int nb = (L + SCAN_CHUNK - 1) / SCAN_CHUNK;

    __shared__ int ls[256];
    __shared__ int pre[32];
    __shared__ int blkExcl;
    int t = threadIdx.x;
    int base = b * SCAN_CHUNK + t * 16;
    int v[16];
    int s = 0;
#pragma unroll
    for (int j = 0; j < 16; ++j) {
        int val = (base + j < L) ? in[base + j] : 0;
        v[j] = s;
        s += val;
    }
    ls[t] = s;
    __syncthreads();
    for (int off = 1; off < 256; off <<= 1) {
        int tv = (t >= off) ? ls[t - off] : 0;
        __syncthreads();
        ls[t] += tv;
        __syncthreads();
    }
    int excl = ls[t] - s;
    int total = ls[255];
    if (t == 255) {
        __threadfence();
        atomicExch(&st[b], total + 1);   // publish early (before lookback)
    }
    if (t < b) {                          // b <= 19 < 32
        int val;
        do { val = atomicAdd(&st[t], 0); } while (val == 0);
        pre[t] = val - 1;
    }
    __syncthreads();
    if (t == 0) {
        int r = 0;
        for (int j = 0; j < b; ++j) r += pre[j];
        blkExcl = r;
    }
    __syncthreads();
    int be = blkExcl;
#pragma unroll
    for (int j = 0; j < 16; ++j)
        if (base + j < L) out[base + j] = be + excl + v[j];
    if (b == nb - 1 && t == 255) out[L] = be + total;
}

// ---- phase 3 (fused): CSR scatter + level-1 message compute + CURSOR
//      rank atomics (issued early; return latency overlaps the spline
//      compute; atomic-unit time overlaps scatB's own HBM/VALU work). ----
__global__ __launch_bounds__(256) void scatB_kernel(
    const int* __restrict__ ei, const float* __restrict__ attr,
    const int* __restrict__ cluster1, const int* __restrict__ cluster2,
    const float2* __restrict__ x, const float* __restrict__ W1,
    const int* __restrict__ doffs, const int* __restrict__ coff,
    const int* __restrict__ c2off,
    int* __restrict__ cur0, int* __restrict__ cur1, int* __restrict__ cur2,
    int* __restrict__ nidx, int* __restrict__ n1idx,
    int4* __restrict__ rec4, int E, int N, int N1)
{
    __shared__ float lw[27 * W1_STRIDE];
    for (int i = threadIdx.x; i < 27 * 16; i += 256)
        lw[(i >> 4) * W1_STRIDE + (i & 15)] = W1[i];
    __syncthreads();

    int i = blockIdx.x * 256 + threadIdx.x;

    // fire all cursor atomics early — returns consumed late
    int s = 0, d = 0, r = 0;
    int c1i = 0, rC = 0;
    int c2i = 0, r2 = 0;
    if (i < E) {
        s = ei[i]; d = ei[E + i];
        r = atomicAdd(&cur0[d], 1);
    }
    if (i < N) {
        c1i = cluster1[i];
        rC = atomicAdd(&cur1[c1i], 1);
    }
    if (i < N1) {
        c2i = cluster2[i];
        r2 = atomicAdd(&cur2[c2i], 1);
    }

    if (i < E) {
        float vx = attr[3 * i] * 2.f, vy = attr[3 * i + 1] * 2.f, vz = attr[3 * i + 2] * 2.f;
        float ix = fmaxf(fminf(floorf(vx), 1.f), 0.f);
        float iy = fmaxf(fminf(floorf(vy), 1.f), 0.f);
        float iz = fmaxf(fminf(floorf(vz), 1.f), 0.f);
        float fx = vx - ix, fy = vy - iy, fz = vz - iz;
        int ibase = (int)ix + 3 * (int)iy + 9 * (int)iz;

        float2 xv = x[s];  // 640 KB, L2-resident random read
        float wxv[2] = {1.f - fx, fx}, wyv[2] = {1.f - fy, fy}, wzv[2] = {1.f - fz, fz};
        float m[8];
#pragma unroll
        for (int o = 0; o < 8; ++o) m[o] = 0.f;
#pragma unroll
        for (int j = 0; j < 8; ++j) {
            int cx = j & 1, cy = (j >> 1) & 1, cz = j >> 2;
            float w = wxv[cx] * wyv[cy] * wzv[cz];
            const float* Wk = &lw[(ibase + cx + 3 * cy + 9 * cz) * W1_STRIDE];
            float a = w * xv.x, bb = w * xv.y;
            const float4 wa0 = *(const float4*)&Wk[0];
            const float4 wa1 = *(const float4*)&Wk[4];
            const float4 wb0 = *(const float4*)&Wk[8];
            const float4 wb1 = *(const float4*)&Wk[12];
            m[0] += a * wa0.x + bb * wb0.x;
            m[1] += a * wa0.y + bb * wb0.y;
            m[2] += a * wa0.z + bb * wb0.z;
            m[3] += a * wa0.w + bb * wb0.w;
            m[4] += a * wa1.x + bb * wb1.x;
            m[5] += a * wa1.y + bb * wb1.y;
            m[6] += a * wa1.z + bb * wb1.z;
            m[7] += a * wa1.w + bb * wb1.w;
        }

        unsigned hfx = __half_as_ushort(__float2half_rn(fx));
        unsigned hfy = __half_as_ushort(__float2half_rn(fy));
        unsigned hfz = __half_as_ushort(__float2half_rn(fz));
        int s2 = cluster1[s];
        int4 ra = make_int4(s2 | (ibase << 16),
                            (int)(hfx | (hfy << 16)), (int)hfz, d);
        __half2 h01 = __floats2half2_rn(m[0], m[1]);
        __half2 h23 = __floats2half2_rn(m[2], m[3]);
        __half2 h45 = __floats2half2_rn(m[4], m[5]);
        __half2 h67 = __floats2half2_rn(m[6], m[7]);
        int4 rb = make_int4(*(int*)&h01, *(int*)&h23, *(int*)&h45, *(int*)&h67);
        int p = doffs[d] + r;
        rec4[2 * (size_t)p]     = ra;
        rec4[2 * (size_t)p + 1] = rb;
    }
    if (i < N)  nidx[coff[c1i] + rC] = i;
    if (i < N1) n1idx[c2off[c2i] + r2] = i;
}

// ---- level-1 reduce: WAVE per node (8 ch x 8 edge-slots). ----
__global__ __launch_bounds__(256) void reduce1_kernel(
    const int* __restrict__ doffs, const unsigned short* __restrict__ recU,
    float* __restrict__ M1, int N)
{
    int lane = threadIdx.x & 63;
    int ch = lane & 7, q = lane >> 3;
    int d = (blockIdx.x << 2) + (threadIdx.x >> 6);
    if (d >= N) return;
    int beg = doffs[d], end = doffs[d + 1];
    float acc = 0.f;
    for (int p = beg + q; p < end; p += 8)
        acc += __half2float(__ushort_as_half(recU[(size_t)p * 16 + 8 + ch]));
    acc += __shfl_xor(acc, 8);
    acc += __shfl_xor(acc, 16);
    acc += __shfl_xor(acc, 32);
    if (q == 0)
        M1[(size_t)d * 8 + ch] = acc / fmaxf((float)(end - beg), 1.f);
}

// ---- level 1 pool: per (cluster, ch); emits x1c (f32) + x1ch (half) ----
__global__ __launch_bounds__(256) void node1_kernel(
    const int* __restrict__ coff, const int* __restrict__ nidx,
    const float* __restrict__ M1, const float2* __restrict__ x,
    const float* __restrict__ root1, const float* __restrict__ b1,
    const int* __restrict__ batch,
    float* __restrict__ x1c, unsigned short* __restrict__ x1chU,
    int* __restrict__ batch1, int N1)
{
    int t = blockIdx.x * 256 + threadIdx.x;
    if (t >= N1 * 8) return;
    int c = t >> 3, ch = t & 7;
    int cb = coff[c], ce = coff[c + 1];
    float r0 = root1[ch], r1 = root1[8 + ch], bo = b1[ch];
    float hm = -INFINITY;
    int bm = 0;
    for (int idx = cb; idx < ce; ++idx) {
        int d = nidx[idx];
        float2 xv = x[d];
        float h = eluf(M1[d * 8 + ch] + xv.x * r0 + xv.y * r1 + bo);
        hm = fmaxf(hm, h);
        bm = max(bm, batch[d]);
    }
    if (ce == cb) hm = 0.f;  // empty cluster -> 0 (ref isfinite mask)
    x1c[t] = hm;
    x1chU[t] = __half_as_ushort(__float2half_rn(hm));
    if (ch == 0) batch1[c] = bm;
}

// ---- level 2 edge blend: thread per (edge, o-quad); fdot2 packed math.
//      R0 LDS layout (measured best: 58.3 us, 7.5M conflict cycles). ----
__global__ __launch_bounds__(256) void edge2m_kernel(
    const int4* __restrict__ rec4, const unsigned short* __restrict__ x1chU,
    const float* __restrict__ W2, unsigned short* __restrict__ msg2h, int E)
{
    __shared__ unsigned lwh[27 * W2H_STRIDE];
    for (int i = threadIdx.x; i < 27 * 64; i += 256) {
        int k = i >> 6, r = i & 63;      // r = o*4 + c2
        int o = r >> 2, c2 = r & 3;
        float a = W2[(k * 8 + 2 * c2) * 16 + o];
        float b = W2[(k * 8 + 2 * c2 + 1) * 16 + o];
        __half2 h = __floats2half2_rn(a, b);
        lwh[k * W2H_STRIDE + r] = *(unsigned*)&h;
    }
    __syncthreads();

    int t = blockIdx.x * 256 + threadIdx.x;
    if (t >= E * 4) return;
    int p = t >> 2, oq = t & 3;          // outputs o0..o0+3, o0 = oq*4
    int4 m = rec4[2 * (size_t)p];        // 4 threads broadcast-load same 16 B
    int s2 = m.x & 0xFFFF;
    int ibase = (m.x >> 16) & 31;
    float fx = hlo(m.y), fy = hhi(m.y), fz = hlo(m.z);

    const uint4 xv4 = *(const uint4*)&x1chU[(size_t)s2 * 8];
    half2v xh0 = uash2(xv4.x), xh1 = uash2(xv4.y),
           xh2 = uash2(xv4.z), xh3 = uash2(xv4.w);

    float wx0 = 1.f - fx, wy0 = 1.f - fy, wz0 = 1.f - fz;
    float acc0 = 0.f, acc1 = 0.f, acc2 = 0.f, acc3 = 0.f;
#pragma unroll
    for (int j = 0; j < 8; ++j) {
        int cx = j & 1, cy = (j >> 1) & 1, cz = j >> 2;
        float w = (cx ? fx : wx0) * (cy ? fy : wy0) * (cz ? fz : wz0);
        int k = ibase + cx + 3 * cy + 9 * cz;
        const unsigned* base = &lwh[k * W2H_STRIDE + oq * 16];
        uint4 v0 = *(const uint4*)(base);
        uint4 v1 = *(const uint4*)(base + 4);
        uint4 v2 = *(const uint4*)(base + 8);
        uint4 v3 = *(const uint4*)(base + 12);
        float s0 = dot2f(xh0, uash2(v0.x), dot2f(xh1, uash2(v0.y),
                   dot2f(xh2, uash2(v0.z), dot2f(xh3, uash2(v0.w), 0.f))));
        float s1 = dot2f(xh0, uash2(v1.x), dot2f(xh1, uash2(v1.y),
                   dot2f(xh2, uash2(v1.z), dot2f(xh3, uash2(v1.w), 0.f))));
        float s2v = dot2f(xh0, uash2(v2.x), dot2f(xh1, uash2(v2.y),
                    dot2f(xh2, uash2(v2.z), dot2f(xh3, uash2(v2.w), 0.f))));
        float s3 = dot2f(xh0, uash2(v3.x), dot2f(xh1, uash2(v3.y),
                   dot2f(xh2, uash2(v3.z), dot2f(xh3, uash2(v3.w), 0.f))));
        acc0 = fmaf(w, s0, acc0);
        acc1 = fmaf(w, s1, acc1);
        acc2 = fmaf(w, s2v, acc2);
        acc3 = fmaf(w, s3, acc3);
    }
    __half2 lo = __floats2half2_rn(acc0, acc1);
    __half2 hi = __floats2half2_rn(acc2, acc3);
    uint2 outv = make_uint2(*(unsigned*)&lo, *(unsigned*)&hi);
    *(uint2*)&msg2h[(size_t)p * 16 + oq * 4] = outv;  // 8-B aligned CSR stream
}

// ---- level 2 reduce: WAVE per cluster (16 o x 4 edge-slots). ----
__global__ __launch_bounds__(256) void reduce2_kernel(
    const int* __restrict__ coff, const int* __restrict__ nidx,
    const int* __restrict__ doffs, const unsigned short* __restrict__ msg2h,
    float* __restrict__ M2, int N1)
{
    int lane = threadIdx.x & 63;
    int o = lane & 15, q = lane >> 4;
    int c = (blockIdx.x << 2) + (threadIdx.x >> 6);
    if (c >= N1) return;
    int cb = coff[c], ce = coff[c + 1];
    float acc = 0.f;
    int cnt = 0;
    for (int idx = cb; idx < ce; ++idx) {
        int d = nidx[idx];
        int beg = doffs[d], end = doffs[d + 1];
        cnt += end - beg;
        for (int p = beg + q; p < end; p += 4)
            acc += __half2float(__ushort_as_half(msg2h[(size_t)p * 16 + o]));
    }
    acc += __shfl_xor(acc, 16);
    acc += __shfl_xor(acc, 32);
    if (q == 0) M2[(size_t)c * 16 + o] = acc / fmaxf((float)cnt, 1.f);
}

// ---- level 2 node + pool + graph sum (LDS-binned; tiny atomic tail) ----
__global__ __launch_bounds__(256) void node2_kernel(
    const int* __restrict__ c2off, const int* __restrict__ n1idx,
    const float* __restrict__ M2, const float* __restrict__ x1c,
    const float* __restrict__ root2, const float* __restrict__ b2,
    const int* __restrict__ batch1,
    float* __restrict__ gsum, float* __restrict__ gcnt, int N2)
{
    __shared__ float ls[16 * 16];
    __shared__ float lc[16];
    for (int i = threadIdx.x; i < 256; i += 256) ls[i] = 0.f;
    if (threadIdx.x < 16) lc[threadIdx.x] = 0.f;
    __syncthreads();

    int c2 = blockIdx.x * 256 + threadIdx.x;
    if (c2 < N2) {
        int cb = c2off[c2], ce = c2off[c2 + 1];
        float hm[16];
#pragma unroll
        for (int o = 0; o < 16; ++o) hm[o] = -INFINITY;
        int bm = 0;
        for (int idx = cb; idx < ce; ++idx) {
            int n1 = n1idx[idx];
            const float4* xr4 = (const float4*)&x1c[(size_t)n1 * 8];
            float4 xa = xr4[0], xb = xr4[1];
            float xr[8] = {xa.x, xa.y, xa.z, xa.w, xb.x, xb.y, xb.z, xb.w};
#pragma unroll
            for (int o = 0; o < 16; ++o) {
                float v = M2[(size_t)n1 * 16 + o] + b2[o];
#pragma unroll
                for (int c8 = 0; c8 < 8; ++c8) v += xr[c8] * root2[c8 * 16 + o];
                hm[o] = fmaxf(hm[o], eluf(v));
            }
            bm = max(bm, batch1[n1]);
        }
        if (ce == cb) {
#pragma unroll
            for (int o = 0; o < 16; ++o) hm[o] = 0.f;
        }
#pragma unroll
        for (int o = 0; o < 16; ++o) atomicAdd(&ls[bm * 16 + o], hm[o]);
        atomicAdd(&lc[bm], 1.f);
    }
    __syncthreads();
    for (int i = threadIdx.x; i < 256; i += 256) unsafeAtomicAdd(&gsum[i], ls[i]);
    if (threadIdx.x < 16) unsafeAtomicAdd(&gcnt[threadIdx.x], lc[threadIdx.x]);
}

// ---- head ----
__global__ __launch_bounds__(256) void head_kernel(
    const float* __restrict__ gsum, const float* __restrict__ gcnt,
    const float* __restrict__ fc1_w, const float* __restrict__ fc1_b,
    const float* __restrict__ fc2_w, const float* __restrict__ fc2_b,
    float* __restrict__ out, int B)
{
    __shared__ float g[16 * 16];
    __shared__ float h1[16 * 64];
    int t = threadIdx.x;
    if (t < B * 16) {
        int b = t >> 4;
        g[t] = gsum[t] / fmaxf(gcnt[b], 1.f);
    }
    __syncthreads();
    for (int j = t; j < B * 64; j += 256) {
        int b = j >> 6, jj = j & 63;
        float s = fc1_b[jj];
#pragma unroll
        for (int c = 0; c < 16; ++c) s += g[b * 16 + c] * fc1_w[c * 64 + jj];
        h1[j] = eluf(s);
    }
    __syncthreads();
    if (t < B) {
        float s = fc2_b[0];
#pragma unroll
        for (int j = 0; j < 64; ++j) s += h1[t * 64 + j] * fc2_w[j];
        out[t] = eluf(s);
    }
}

extern "C" void kernel_launch(void* const* d_in, const int* in_sizes, int n_in,
                              void* d_out, int out_size, void* d_ws, size_t ws_size,
                              hipStream_t stream)
{
    const float* x        = (const float*)d_in[0];
    const int*   ei       = (const int*)  d_in[1];
    const float* attr     = (const float*)d_in[2];
    const int*   batch    = (const int*)  d_in[3];
    const int*   cluster1 = (const int*)  d_in[4];
    const int*   cluster2 = (const int*)  d_in[5];
    const float* W1       = (const float*)d_in[6];
    const float* root1    = (const float*)d_in[7];
    const float* b1       = (const float*)d_in[8];
    const float* W2       = (const float*)d_in[9];
    const float* root2    = (const float*)d_in[10];
    const float* b2       = (const float*)d_in[11];
    const float* fc1_w    = (const float*)d_in[12];
    const float* fc1_b    = (const float*)d_in[13];
    const float* fc2_w    = (const float*)d_in[14];
    const float* fc2_b    = (const float*)d_in[15];

    const int N  = in_sizes[0] / 2;
    const int E  = in_sizes[1] / 2;
    const int N1 = in_sizes[5];
    const int N2 = N1 / 2;
    const int B  = out_size;

    const int nb0 = (N  + SCAN_CHUNK - 1) / SCAN_CHUNK;
    const int nb1 = (N1 + SCAN_CHUNK - 1) / SCAN_CHUNK;
    const int nb2 = (N2 + SCAN_CHUNK - 1) / SCAN_CHUNK;

    int* wi = (int*)d_ws;
    size_t off = 0;
    auto alloc = [&](size_t n, size_t align = 1) {
        off = (off + align - 1) & ~(align - 1);
        size_t r = off; off += n; return r;
    };
    // zero-init region
    int*   deg    = wi + alloc(N);
    int*   cdeg   = wi + alloc(N1);
    int*   c2deg  = wi + alloc(N2);
    int*   cur0   = wi + alloc(N);
    int*   cur1   = wi + alloc(N1);
    int*   cur2   = wi + alloc(N2);
    float* gsum   = (float*)(wi + alloc((size_t)B * 16));
    float* gcnt   = (float*)(wi + alloc(B));
    int*   st0    = wi + alloc(32);
    int*   st1    = wi + alloc(32);
    int*   st2    = wi + alloc(32);
    const size_t zcount = off;
    // rest (fully overwritten before read)
    int*   doffs  = wi + alloc(N + 1);
    int*   coff   = wi + alloc(N1 + 1);
    int*   c2off  = wi + alloc(N2 + 1);
    int*   nidx   = wi + alloc(N);
    int*   n1idx  = wi + alloc(N1);
    int4*  rec4   = (int4*)(wi + alloc((size_t)E * 8, 8));   // 32-B records
    unsigned short* msg2h = (unsigned short*)(wi + alloc((size_t)E * 8, 4));
    float* M1     = (float*)(wi + alloc((size_t)N * 8, 4));
    float* x1c    = (float*)(wi + alloc((size_t)N1 * 8, 4));
    unsigned short* x1chU = (unsigned short*)(wi + alloc((size_t)N1 * 4, 4));
    int*   batch1 = wi + alloc(N1);
    float* M2     = (float*)(wi + alloc((size_t)N1 * 16, 4));
    (void)ws_size;  // peak ~96 MB (R5-proven capacity ~113 MB)

    hipMemsetAsync(d_ws, 0, zcount * sizeof(int), stream);

    const int eb = (E + 255) / 256;
    hist_kernel<<<eb, 256, 0, stream>>>(ei, cluster1, cluster2,
                                        deg, cdeg, c2deg, E, N, N1);
    scan_one<<<nb0 + nb1 + nb2, 256, 0, stream>>>(deg, doffs, st0, N, nb0,
                                                  cdeg, coff, st1, N1, nb1,
                                                  c2deg, c2off, st2, N2);
    scatB_kernel<<<eb, 256, 0, stream>>>(ei, attr, cluster1, cluster2,
                                         (const float2*)x, W1,
                                         doffs, coff, c2off,
                                         cur0, cur1, cur2,
                                         nidx, n1idx, rec4, E, N, N1);
    reduce1_kernel<<<(N + 3) / 4, 256, 0, stream>>>(
        doffs, (const unsigned short*)rec4, M1, N);
    node1_kernel<<<(N1 * 8 + 255) / 256, 256, 0, stream>>>(
        coff, nidx, M1, (const float2*)x, root1, b1, batch,
        x1c, x1chU, batch1, N1);
    edge2m_kernel<<<(E * 4 + 255) / 256, 256, 0, stream>>>(
        rec4, x1chU, W2, msg2h, E);
    reduce2_kernel<<<(N1 + 3) / 4, 256, 0, stream>>>(
        coff, nidx, doffs, msg2h, M2, N1);
    node2_kernel<<<(N2 + 255) / 256, 256, 0, stream>>>(
        c2off, n1idx, M2, x1c, root2, b2, batch1, gsum, gcnt, N2);
    head_kernel<<<1, 256, 0, stream>>>(gsum, gcnt, fc1_w, fc1_b, fc2_w, fc2_b,
                                       (float*)d_out, B);
}

// Round 12
// 339.948 us; speedup vs baseline: 1.2647x; 1.0982x over previous
//
#include <hip/hip_runtime.h>
#include <hip/hip_fp16.h>
#include <math.h>

// ---------------------------------------------------------------------------
// Net_75505525064500 — round 21 (R18 base + widened reduce1/reduce2 loads).
// Ledger of failed approaches (do NOT retry):
//   R12 cluster-granularity serial fusion: parallelism collapse, 154 us.
//   R13 looped wave-per-node msg2 (LDS in loop): 160 us.
//   R14 LDS-atomic Y-bins: collision storm, 508 us.
//   R15 edge2m relayout: random-k b128 rows have no static bank fix.
//   R17 node2R: 3-deep indirection loop, 149 us.
//   R19 edge2Y register factorization: serial all-lane weights, 167 us.
//   R20 cursor atomics in scatB + non-returning hist: wall is raw atomic
//     UNIT throughput (~24 G/s); overlap impossible; hist ~58 is final.
// R18 best: 347.9 us. Known mass: edge2m 58.8 + hist ~58 + scatB ~56.
// R21: widen reduce1 (2B/lane, 8 slots/round -> uint2/lane, 32 slots/round,
//   parity shfl tree) and reduce2 (2B/lane, 4 slots -> uint/lane, 8 slots,
//   o-pair shfl tree). Total delta localizes the hidden ~175 us mid-field.
// Chain: memset -> hist -> scan_one -> scatB -> reduce1 -> node1 ->
//        edge2m -> reduce2 -> node2 -> head.
// Sizes: N=80000 (Cin=2), E=1280000, N1=40000 (C=8), N2=20000 (C=16), B=16.
// ---------------------------------------------------------------------------

__device__ __forceinline__ float eluf(float x) {
    return x > 0.f ? x : (expf(x) - 1.f);
}

__device__ __forceinline__ float hlo(int v) {
    __half2 h; *(int*)&h = v; return __low2float(h);
}
__device__ __forceinline__ float hhi(int v) {
    __half2 h; *(int*)&h = v; return __high2float(h);
}

__device__ __forceinline__ float hlou(unsigned v) {
    __half2 h; *(unsigned*)&h = v; return __low2float(h);
}
__device__ __forceinline__ float hhiu(unsigned v) {
    __half2 h; *(unsigned*)&h = v; return __high2float(h);
}

typedef _Float16 half2v __attribute__((ext_vector_type(2)));

__device__ __forceinline__ half2v uash2(unsigned u) {
    half2v h; *(unsigned*)&h = u; return h;
}

__device__ __forceinline__ float dot2f(half2v a, half2v b, float c) {
#if __has_builtin(__builtin_amdgcn_fdot2)
    return __builtin_amdgcn_fdot2(a, b, c, false);
#else
    return c + (float)a[0] * (float)b[0] + (float)a[1] * (float)b[1];
#endif
}

#define W1_STRIDE 20
#define W2H_STRIDE 68  // dwords per k-row: 64 payload (16 o x 4 half2) + 4 pad

// rec per edge (2 x int4 = 32 B, one sector):
//   [0].x = s2 | ibase<<16    (s2 < 65536, ibase < 27)
//   [0].y = half(fx) | half(fy)<<16
//   [0].z = half(fz)
//   [0].w = d (dst node id; spare)
//   [1]   = msg1 as 8 halves (ch pairs 01,23,45,67)

// ---- phase 1: histograms + within-bin ranks (atomic unit throughput
//      wall ~24 G/s — structural floor, R11/R20-proven). ----
__global__ __launch_bounds__(256) void hist_kernel(
    const int* __restrict__ ei, const int* __restrict__ cluster1,
    const int* __restrict__ cluster2,
    int* __restrict__ deg, int* __restrict__ rank,
    int* __restrict__ cdeg, int* __restrict__ rankC,
    int* __restrict__ c2deg, int* __restrict__ rank2,
    int E, int N, int N1)
{
    int i = blockIdx.x * 256 + threadIdx.x;
    if (i < E)  rank[i]  = atomicAdd(&deg[ei[E + i]], 1);
    if (i < N)  rankC[i] = atomicAdd(&cdeg[cluster1[i]], 1);
    if (i < N1) rank2[i] = atomicAdd(&c2deg[cluster2[i]], 1);
}

// ---- phase 2: single-pass exclusive scan, 3 arrays in one launch. ----
#define SCAN_CHUNK 4096

__global__ __launch_bounds__(256) void scan_one(
    const int* __restrict__ in0, int* __restrict__ out0, int* __restrict__ st0, int L0, int nb0,
    const int* __restrict__ in1, int* __restrict__ out1, int* __restrict__ st1, int L1, int nb1,
    const int* __restrict__ in2, int* __restrict__ out2, int* __restrict__ st2, int L2)
{
    int b = blockIdx.x;
    const int* in; int* out; int* st; int L;
    if (b < nb0)            { in = in0; out = out0; st = st0; L = L0; }
    else if (b < nb0 + nb1) { b -= nb0; in = in1; out = out1; st = st1; L = L1; }
    else                    { b -= nb0 + nb1; in = in2; out = out2; st = st2; L = L2; }
    int nb = (L + SCAN_CHUNK - 1) / SCAN_CHUNK;

    __shared__ int ls[256];
    __shared__ int pre[32];
    __shared__ int blkExcl;
    int t = threadIdx.x;
    int base = b * SCAN_CHUNK + t * 16;
    int v[16];
    int s = 0;
#pragma unroll
    for (int j = 0; j < 16; ++j) {
        int val = (base + j < L) ? in[base + j] : 0;
        v[j] = s;
        s += val;
    }
    ls[t] = s;
    __syncthreads();
    for (int off = 1; off < 256; off <<= 1) {
        int tv = (t >= off) ? ls[t - off] : 0;
        __syncthreads();
        ls[t] += tv;
        __syncthreads();
    }
    int excl = ls[t] - s;
    int total = ls[255];
    if (t == 255) {
        __threadfence();
        atomicExch(&st[b], total + 1);   // publish early (before lookback)
    }
    if (t < b) {                          // b <= 19 < 32
        int val;
        do { val = atomicAdd(&st[t], 0); } while (val == 0);
        pre[t] = val - 1;
    }
    __syncthreads();
    if (t == 0) {
        int r = 0;
        for (int j = 0; j < b; ++j) r += pre[j];
        blkExcl = r;
    }
    __syncthreads();
    int be = blkExcl;
#pragma unroll
    for (int j = 0; j < 16; ++j)
        if (base + j < L) out[base + j] = be + excl + v[j];
    if (b == nb - 1 && t == 255) out[L] = be + total;
}

// ---- phase 3 (fused): CSR scatter + level-1 message compute. ----
__global__ __launch_bounds__(256) void scatB_kernel(
    const int* __restrict__ ei, const float* __restrict__ attr,
    const int* __restrict__ cluster1, const int* __restrict__ cluster2,
    const float2* __restrict__ x, const float* __restrict__ W1,
    const int* __restrict__ doffs, const int* __restrict__ rank,
    const int* __restrict__ coff, const int* __restrict__ rankC,
    const int* __restrict__ c2off, const int* __restrict__ rank2,
    int* __restrict__ nidx, int* __restrict__ n1idx,
    int4* __restrict__ rec4, int E, int N, int N1)
{
    __shared__ float lw[27 * W1_STRIDE];
    for (int i = threadIdx.x; i < 27 * 16; i += 256)
        lw[(i >> 4) * W1_STRIDE + (i & 15)] = W1[i];
    __syncthreads();

    int i = blockIdx.x * 256 + threadIdx.x;
    if (i < E) {
        int s = ei[i], d = ei[E + i];
        int p = doffs[d] + rank[i];

        float vx = attr[3 * i] * 2.f, vy = attr[3 * i + 1] * 2.f, vz = attr[3 * i + 2] * 2.f;
        float ix = fmaxf(fminf(floorf(vx), 1.f), 0.f);
        float iy = fmaxf(fminf(floorf(vy), 1.f), 0.f);
        float iz = fmaxf(fminf(floorf(vz), 1.f), 0.f);
        float fx = vx - ix, fy = vy - iy, fz = vz - iz;
        int ibase = (int)ix + 3 * (int)iy + 9 * (int)iz;

        float2 xv = x[s];  // 640 KB, L2-resident random read
        float wxv[2] = {1.f - fx, fx}, wyv[2] = {1.f - fy, fy}, wzv[2] = {1.f - fz, fz};
        float m[8];
#pragma unroll
        for (int o = 0; o < 8; ++o) m[o] = 0.f;
#pragma unroll
        for (int j = 0; j < 8; ++j) {
            int cx = j & 1, cy = (j >> 1) & 1, cz = j >> 2;
            float w = wxv[cx] * wyv[cy] * wzv[cz];
            const float* Wk = &lw[(ibase + cx + 3 * cy + 9 * cz) * W1_STRIDE];
            float a = w * xv.x, bb = w * xv.y;
            const float4 wa0 = *(const float4*)&Wk[0];
            const float4 wa1 = *(const float4*)&Wk[4];
            const float4 wb0 = *(const float4*)&Wk[8];
            const float4 wb1 = *(const float4*)&Wk[12];
            m[0] += a * wa0.x + bb * wb0.x;
            m[1] += a * wa0.y + bb * wb0.y;
            m[2] += a * wa0.z + bb * wb0.z;
            m[3] += a * wa0.w + bb * wb0.w;
            m[4] += a * wa1.x + bb * wb1.x;
            m[5] += a * wa1.y + bb * wb1.y;
            m[6] += a * wa1.z + bb * wb1.z;
            m[7] += a * wa1.w + bb * wb1.w;
        }

        unsigned hfx = __half_as_ushort(__float2half_rn(fx));
        unsigned hfy = __half_as_ushort(__float2half_rn(fy));
        unsigned hfz = __half_as_ushort(__float2half_rn(fz));
        int s2 = cluster1[s];
        int4 ra = make_int4(s2 | (ibase << 16),
                            (int)(hfx | (hfy << 16)), (int)hfz, d);
        __half2 h01 = __floats2half2_rn(m[0], m[1]);
        __half2 h23 = __floats2half2_rn(m[2], m[3]);
        __half2 h45 = __floats2half2_rn(m[4], m[5]);
        __half2 h67 = __floats2half2_rn(m[6], m[7]);
        int4 rb = make_int4(*(int*)&h01, *(int*)&h23, *(int*)&h45, *(int*)&h67);
        rec4[2 * (size_t)p]     = ra;
        rec4[2 * (size_t)p + 1] = rb;
    }
    if (i < N)  nidx[coff[cluster1[i]] + rankC[i]] = i;
    if (i < N1) n1idx[c2off[cluster2[i]] + rank2[i]] = i;
}

// ---- level-1 reduce: WAVE per node, WIDE loads. Lane = (slot, half):
//      uint2 (4 halves) per lane -> 32 slots/round (was 8 at 2 B/lane).
//      Parity-preserving shfl_xor tree {2,4,8,16,32}; float4 stores. ----
__global__ __launch_bounds__(256) void reduce1_kernel(
    const int* __restrict__ doffs, const unsigned short* __restrict__ recU,
    float* __restrict__ M1, int N)
{
    int lane = threadIdx.x & 63;
    int part = lane & 1;            // 0: ch0-3, 1: ch4-7
    int d = (blockIdx.x << 2) + (threadIdx.x >> 6);
    if (d >= N) return;
    int beg = doffs[d], end = doffs[d + 1];
    float a0 = 0.f, a1 = 0.f, a2 = 0.f, a3 = 0.f;
    for (int p0 = beg; p0 < end; p0 += 32) {
        int s = p0 + (lane >> 1);
        if (s < end) {
            uint2 u = *(const uint2*)&recU[(size_t)s * 16 + 8 + part * 4];
            a0 += hlou(u.x); a1 += hhiu(u.x);
            a2 += hlou(u.y); a3 += hhiu(u.y);
        }
    }
#pragma unroll
    for (int m = 2; m <= 32; m <<= 1) {
        a0 += __shfl_xor(a0, m);
        a1 += __shfl_xor(a1, m);
        a2 += __shfl_xor(a2, m);
        a3 += __shfl_xor(a3, m);
    }
    float inv = 1.f / fmaxf((float)(end - beg), 1.f);
    if (lane < 2)
        *(float4*)&M1[(size_t)d * 8 + part * 4] =
            make_float4(a0 * inv, a1 * inv, a2 * inv, a3 * inv);
}

// ---- level 1 pool: per (cluster, ch); emits x1c (f32) + x1ch (half) ----
__global__ __launch_bounds__(256) void node1_kernel(
    const int* __restrict__ coff, const int* __restrict__ nidx,
    const float* __restrict__ M1, const float2* __restrict__ x,
    const float* __restrict__ root1, const float* __restrict__ b1,
    const int* __restrict__ batch,
    float* __restrict__ x1c, unsigned short* __restrict__ x1chU,
    int* __restrict__ batch1, int N1)
{
    int t = blockIdx.x * 256 + threadIdx.x;
    if (t >= N1 * 8) return;
    int c = t >> 3, ch = t & 7;
    int cb = coff[c], ce = coff[c + 1];
    float r0 = root1[ch], r1 = root1[8 + ch], bo = b1[ch];
    float hm = -INFINITY;
    int bm = 0;
    for (int idx = cb; idx < ce; ++idx) {
        int d = nidx[idx];
        float2 xv = x[d];
        float h = eluf(M1[d * 8 + ch] + xv.x * r0 + xv.y * r1 + bo);
        hm = fmaxf(hm, h);
        bm = max(bm, batch[d]);
    }
    if (ce == cb) hm = 0.f;  // empty cluster -> 0 (ref isfinite mask)
    x1c[t] = hm;
    x1chU[t] = __half_as_ushort(__float2half_rn(hm));
    if (ch == 0) batch1[c] = bm;
}

// ---- level 2 edge blend: thread per (edge, o-quad); fdot2 packed math.
//      R0 LDS layout (measured best: 58.3 us, 7.5M conflict cycles). ----
__global__ __launch_bounds__(256) void edge2m_kernel(
    const int4* __restrict__ rec4, const unsigned short* __restrict__ x1chU,
    const float* __restrict__ W2, unsigned short* __restrict__ msg2h, int E)
{
    __shared__ unsigned lwh[27 * W2H_STRIDE];
    for (int i = threadIdx.x; i < 27 * 64; i += 256) {
        int k = i >> 6, r = i & 63;      // r = o*4 + c2
        int o = r >> 2, c2 = r & 3;
        float a = W2[(k * 8 + 2 * c2) * 16 + o];
        float b = W2[(k * 8 + 2 * c2 + 1) * 16 + o];
        __half2 h = __floats2half2_rn(a, b);
        lwh[k * W2H_STRIDE + r] = *(unsigned*)&h;
    }
    __syncthreads();

    int t = blockIdx.x * 256 + threadIdx.x;
    if (t >= E * 4) return;
    int p = t >> 2, oq = t & 3;          // outputs o0..o0+3, o0 = oq*4
    int4 m = rec4[2 * (size_t)p];        // 4 threads broadcast-load same 16 B
    int s2 = m.x & 0xFFFF;
    int ibase = (m.x >> 16) & 31;
    float fx = hlo(m.y), fy = hhi(m.y), fz = hlo(m.z);

    const uint4 xv4 = *(const uint4*)&x1chU[(size_t)s2 * 8];
    half2v xh0 = uash2(xv4.x), xh1 = uash2(xv4.y),
           xh2 = uash2(xv4.z), xh3 = uash2(xv4.w);

    float wx0 = 1.f - fx, wy0 = 1.f - fy, wz0 = 1.f - fz;
    float acc0 = 0.f, acc1 = 0.f, acc2 = 0.f, acc3 = 0.f;
#pragma unroll
    for (int j = 0; j < 8; ++j) {
        int cx = j & 1, cy = (j >> 1) & 1, cz = j >> 2;
        float w = (cx ? fx : wx0) * (cy ? fy : wy0) * (cz ? fz : wz0);
        int k = ibase + cx + 3 * cy + 9 * cz;
        const unsigned* base = &lwh[k * W2H_STRIDE + oq * 16];
        uint4 v0 = *(const uint4*)(base);
        uint4 v1 = *(const uint4*)(base + 4);
        uint4 v2 = *(const uint4*)(base + 8);
        uint4 v3 = *(const uint4*)(base + 12);
        float s0 = dot2f(xh0, uash2(v0.x), dot2f(xh1, uash2(v0.y),
                   dot2f(xh2, uash2(v0.z), dot2f(xh3, uash2(v0.w), 0.f))));
        float s1 = dot2f(xh0, uash2(v1.x), dot2f(xh1, uash2(v1.y),
                   dot2f(xh2, uash2(v1.z), dot2f(xh3, uash2(v1.w), 0.f))));
        float s2v = dot2f(xh0, uash2(v2.x), dot2f(xh1, uash2(v2.y),
                    dot2f(xh2, uash2(v2.z), dot2f(xh3, uash2(v2.w), 0.f))));
        float s3 = dot2f(xh0, uash2(v3.x), dot2f(xh1, uash2(v3.y),
                   dot2f(xh2, uash2(v3.z), dot2f(xh3, uash2(v3.w), 0.f))));
        acc0 = fmaf(w, s0, acc0);
        acc1 = fmaf(w, s1, acc1);
        acc2 = fmaf(w, s2v, acc2);
        acc3 = fmaf(w, s3, acc3);
    }
    __half2 lo = __floats2half2_rn(acc0, acc1);
    __half2 hi = __floats2half2_rn(acc2, acc3);
    uint2 outv = make_uint2(*(unsigned*)&lo, *(unsigned*)&hi);
    *(uint2*)&msg2h[(size_t)p * 16 + oq * 4] = outv;  // 8-B aligned CSR stream
}

// ---- level 2 reduce: WAVE per cluster, WIDE loads. Lane = (slot, o-pair):
//      uint (2 halves) per lane -> 8 slots/round (was 4 at 2 B/lane).
//      shfl_xor tree {8,16,32} keeps o-pair; float2 stores. ----
__global__ __launch_bounds__(256) void reduce2_kernel(
    const int* __restrict__ coff, const int* __restrict__ nidx,
    const int* __restrict__ doffs, const unsigned short* __restrict__ msg2h,
    float* __restrict__ M2, int N1)
{
    int lane = threadIdx.x & 63;
    int opos = lane & 7;            // o-pair: o = 2*opos, 2*opos+1
    int c = (blockIdx.x << 2) + (threadIdx.x >> 6);
    if (c >= N1) return;
    int cb = coff[c], ce = coff[c + 1];
    float a0 = 0.f, a1 = 0.f;
    int cnt = 0;
    for (int idx = cb; idx < ce; ++idx) {
        int d = nidx[idx];
        int beg = doffs[d], end = doffs[d + 1];
        cnt += end - beg;
        for (int p0 = beg; p0 < end; p0 += 8) {
            int s = p0 + (lane >> 3);
            if (s < end) {
                unsigned u = *(const unsigned*)&msg2h[(size_t)s * 16 + opos * 2];
                a0 += hlou(u); a1 += hhiu(u);
            }
        }
    }
#pragma unroll
    for (int m = 8; m <= 32; m <<= 1) {
        a0 += __shfl_xor(a0, m);
        a1 += __shfl_xor(a1, m);
    }
    float inv = 1.f / fmaxf((float)cnt, 1.f);
    if (lane < 8)
        *(float2*)&M2[(size_t)c * 16 + opos * 2] = make_float2(a0 * inv, a1 * inv);
}

// ---- level 2 node + pool + graph sum (LDS-binned; tiny atomic tail) ----
__global__ __launch_bounds__(256) void node2_kernel(
    const int* __restrict__ c2off, const int* __restrict__ n1idx,
    const float* __restrict__ M2, const float* __restrict__ x1c,
    const float* __restrict__ root2, const float* __restrict__ b2,
    const int* __restrict__ batch1,
    float* __restrict__ gsum, float* __restrict__ gcnt, int N2)
{
    __shared__ float ls[16 * 16];
    __shared__ float lc[16];
    for (int i = threadIdx.x; i < 256; i += 256) ls[i] = 0.f;
    if (threadIdx.x < 16) lc[threadIdx.x] = 0.f;
    __syncthreads();

    int c2 = blockIdx.x * 256 + threadIdx.x;
    if (c2 < N2) {
        int cb = c2off[c2], ce = c2off[c2 + 1];
        float hm[16];
#pragma unroll
        for (int o = 0; o < 16; ++o) hm[o] = -INFINITY;
        int bm = 0;
        for (int idx = cb; idx < ce; ++idx) {
            int n1 = n1idx[idx];
            const float4* xr4 = (const float4*)&x1c[(size_t)n1 * 8];
            float4 xa = xr4[0], xb = xr4[1];
            float xr[8] = {xa.x, xa.y, xa.z, xa.w, xb.x, xb.y, xb.z, xb.w};
#pragma unroll
            for (int o = 0; o < 16; ++o) {
                float v = M2[(size_t)n1 * 16 + o] + b2[o];
#pragma unroll
                for (int c8 = 0; c8 < 8; ++c8) v += xr[c8] * root2[c8 * 16 + o];
                hm[o] = fmaxf(hm[o], eluf(v));
            }
            bm = max(bm, batch1[n1]);
        }
        if (ce == cb) {
#pragma unroll
            for (int o = 0; o < 16; ++o) hm[o] = 0.f;
        }
#pragma unroll
        for (int o = 0; o < 16; ++o) atomicAdd(&ls[bm * 16 + o], hm[o]);
        atomicAdd(&lc[bm], 1.f);
    }
    __syncthreads();
    for (int i = threadIdx.x; i < 256; i += 256) unsafeAtomicAdd(&gsum[i], ls[i]);
    if (threadIdx.x < 16) unsafeAtomicAdd(&gcnt[threadIdx.x], lc[threadIdx.x]);
}

// ---- head ----
__global__ __launch_bounds__(256) void head_kernel(
    const float* __restrict__ gsum, const float* __restrict__ gcnt,
    const float* __restrict__ fc1_w, const float* __restrict__ fc1_b,
    const float* __restrict__ fc2_w, const float* __restrict__ fc2_b,
    float* __restrict__ out, int B)
{
    __shared__ float g[16 * 16];
    __shared__ float h1[16 * 64];
    int t = threadIdx.x;
    if (t < B * 16) {
        int b = t >> 4;
        g[t] = gsum[t] / fmaxf(gcnt[b], 1.f);
    }
    __syncthreads();
    for (int j = t; j < B * 64; j += 256) {
        int b = j >> 6, jj = j & 63;
        float s = fc1_b[jj];
#pragma unroll
        for (int c = 0; c < 16; ++c) s += g[b * 16 + c] * fc1_w[c * 64 + jj];
        h1[j] = eluf(s);
    }
    __syncthreads();
    if (t < B) {
        float s = fc2_b[0];
#pragma unroll
        for (int j = 0; j < 64; ++j) s += h1[t * 64 + j] * fc2_w[j];
        out[t] = eluf(s);
    }
}

extern "C" void kernel_launch(void* const* d_in, const int* in_sizes, int n_in,
                              void* d_out, int out_size, void* d_ws, size_t ws_size,
                              hipStream_t stream)
{
    const float* x        = (const float*)d_in[0];
    const int*   ei       = (const int*)  d_in[1];
    const float* attr     = (const float*)d_in[2];
    const int*   batch    = (const int*)  d_in[3];
    const int*   cluster1 = (const int*)  d_in[4];
    const int*   cluster2 = (const int*)  d_in[5];
    const float* W1       = (const float*)d_in[6];
    const float* root1    = (const float*)d_in[7];
    const float* b1       = (const float*)d_in[8];
    const float* W2       = (const float*)d_in[9];
    const float* root2    = (const float*)d_in[10];
    const float* b2       = (const float*)d_in[11];
    const float* fc1_w    = (const float*)d_in[12];
    const float* fc1_b    = (const float*)d_in[13];
    const float* fc2_w    = (const float*)d_in[14];
    const float* fc2_b    = (const float*)d_in[15];

    const int N  = in_sizes[0] / 2;
    const int E  = in_sizes[1] / 2;
    const int N1 = in_sizes[5];
    const int N2 = N1 / 2;
    const int B  = out_size;

    const int nb0 = (N  + SCAN_CHUNK - 1) / SCAN_CHUNK;
    const int nb1 = (N1 + SCAN_CHUNK - 1) / SCAN_CHUNK;
    const int nb2 = (N2 + SCAN_CHUNK - 1) / SCAN_CHUNK;

    int* wi = (int*)d_ws;
    size_t off = 0;
    auto alloc = [&](size_t n, size_t align = 1) {
        off = (off + align - 1) & ~(align - 1);
        size_t r = off; off += n; return r;
    };
    // zero-init region
    int*   deg    = wi + alloc(N);
    int*   cdeg   = wi + alloc(N1);
    int*   c2deg  = wi + alloc(N2);
    float* gsum   = (float*)(wi + alloc((size_t)B * 16));
    float* gcnt   = (float*)(wi + alloc(B));
    int*   st0    = wi + alloc(32);
    int*   st1    = wi + alloc(32);
    int*   st2    = wi + alloc(32);
    const size_t zcount = off;
    // rest (fully overwritten before read)
    int*   doffs  = wi + alloc(N + 1);
    int*   coff   = wi + alloc(N1 + 1);
    int*   c2off  = wi + alloc(N2 + 1);
    int*   rank   = wi + alloc(E);
    int*   rankC  = wi + alloc(N);
    int*   rank2  = wi + alloc(N1);
    int*   nidx   = wi + alloc(N);
    int*   n1idx  = wi + alloc(N1);
    int4*  rec4   = (int4*)(wi + alloc((size_t)E * 8, 8));   // 32-B records
    unsigned short* msg2h = (unsigned short*)(wi + alloc((size_t)E * 8, 4));
    float* M1     = (float*)(wi + alloc((size_t)N * 8, 4));
    float* x1c    = (float*)(wi + alloc((size_t)N1 * 8, 4));
    unsigned short* x1chU = (unsigned short*)(wi + alloc((size_t)N1 * 4, 4));
    int*   batch1 = wi + alloc(N1);
    float* M2     = (float*)(wi + alloc((size_t)N1 * 16, 4));
    (void)ws_size;  // peak ~96 MB (R5-proven capacity ~113 MB)

    hipMemsetAsync(d_ws, 0, zcount * sizeof(int), stream);

    const int eb = (E + 255) / 256;
    hist_kernel<<<eb, 256, 0, stream>>>(ei, cluster1, cluster2,
                                        deg, rank, cdeg, rankC, c2deg, rank2, E, N, N1);
    scan_one<<<nb0 + nb1 + nb2, 256, 0, stream>>>(deg, doffs, st0, N, nb0,
                                                  cdeg, coff, st1, N1, nb1,
                                                  c2deg, c2off, st2, N2);
    scatB_kernel<<<eb, 256, 0, stream>>>(ei, attr, cluster1, cluster2,
                                         (const float2*)x, W1,
                                         doffs, rank, coff, rankC, c2off, rank2,
                                         nidx, n1idx, rec4, E, N, N1);
    reduce1_kernel<<<(N + 3) / 4, 256, 0, stream>>>(
        doffs, (const unsigned short*)rec4, M1, N);
    node1_kernel<<<(N1 * 8 + 255) / 256, 256, 0, stream>>>(
        coff, nidx, M1, (const float2*)x, root1, b1, batch,
        x1c, x1chU, batch1, N1);
    edge2m_kernel<<<(E * 4 + 255) / 256, 256, 0, stream>>>(
        rec4, x1chU, W2, msg2h, E);
    reduce2_kernel<<<(N1 + 3) / 4, 256, 0, stream>>>(
        coff, nidx, doffs, msg2h, M2, N1);
    node2_kernel<<<(N2 + 255) / 256, 256, 0, stream>>>(
        c2off, n1idx, M2, x1c, root2, b2, batch1, gsum, gcnt, N2);
    head_kernel<<<1, 256, 0, stream>>>(gsum, gcnt, fc1_w, fc1_b, fc2_w, fc2_b,
                                       (float*)d_out, B);
}

// Round 13
// 333.618 us; speedup vs baseline: 1.2887x; 1.0190x over previous
//
#include <hip/hip_runtime.h>
#include <hip/hip_fp16.h>
#include <math.h>

// ---------------------------------------------------------------------------
// Net_75505525064500 — round 22 (R21 base + ibase-sorted edge2m).
// Ledger of failed approaches (do NOT retry):
//   R12 cluster-granularity serial fusion: parallelism collapse, 154 us.
//   R13 looped wave-per-node msg2 (LDS in loop): 160 us.
//   R14 LDS-atomic Y-bins (64 f32 atomics/thread, ~15-way collisions): 508 us.
//   R15 edge2m static relayout: random-k b128 rows have no static bank fix.
//   R17 node2R 3-deep indirection loop: 149 us.
//   R19 edge2Y register factorization: serial all-lane weights, 167 us.
//   R20 cursor atomics / non-returning hist: wall is raw atomic UNIT
//     throughput (~24 G/s); hist ~58 is final.
// R21 best: 339.9 us (edge2m 59 / hist ~58 / scatB ~56; mid-field ~15-25 ea).
// R22: edge2m DS-pipe fix. ibase has only 8 values ({0,1,3,4,9,10,12,13});
//   block=1024 (256 edges x 4 oq) counting-sorts its edges by ibase (1 int
//   LDS-atomic/thread — NOT the R14 pattern), so each wave's 16 edge-slots
//   share the k-row per j-iter -> W2 b128 reads become 4-8-way broadcasts
//   (~conflict-free) instead of ~16 scattered rows. DS time ~45 -> ~15 us.
//   Processing order is free (pure map over CSR slots); writes scatter only
//   within an 8-KB window (L2-absorbed).
// Chain: memset -> hist -> scan_one -> scatB -> reduce1 -> node1 ->
//        edge2m -> reduce2 -> node2 -> head.
// Sizes: N=80000 (Cin=2), E=1280000, N1=40000 (C=8), N2=20000 (C=16), B=16.
// ---------------------------------------------------------------------------

__device__ __forceinline__ float eluf(float x) {
    return x > 0.f ? x : (expf(x) - 1.f);
}

__device__ __forceinline__ float hlo(int v) {
    __half2 h; *(int*)&h = v; return __low2float(h);
}
__device__ __forceinline__ float hhi(int v) {
    __half2 h; *(int*)&h = v; return __high2float(h);
}

__device__ __forceinline__ float hlou(unsigned v) {
    __half2 h; *(unsigned*)&h = v; return __low2float(h);
}
__device__ __forceinline__ float hhiu(unsigned v) {
    __half2 h; *(unsigned*)&h = v; return __high2float(h);
}

typedef _Float16 half2v __attribute__((ext_vector_type(2)));

__device__ __forceinline__ half2v uash2(unsigned u) {
    half2v h; *(unsigned*)&h = u; return h;
}

__device__ __forceinline__ float dot2f(half2v a, half2v b, float c) {
#if __has_builtin(__builtin_amdgcn_fdot2)
    return __builtin_amdgcn_fdot2(a, b, c, false);
#else
    return c + (float)a[0] * (float)b[0] + (float)a[1] * (float)b[1];
#endif
}

#define W1_STRIDE 20
#define W2H_STRIDE 68  // dwords per k-row: 64 payload (16 o x 4 half2) + 4 pad

// rec per edge (2 x int4 = 32 B, one sector):
//   [0].x = s2 | ibase<<16    (s2 < 65536, ibase < 27)
//   [0].y = half(fx) | half(fy)<<16
//   [0].z = half(fz)
//   [0].w = d (dst node id; spare)
//   [1]   = msg1 as 8 halves (ch pairs 01,23,45,67)

// ---- phase 1: histograms + within-bin ranks (atomic unit throughput
//      wall ~24 G/s — structural floor, R11/R20-proven). ----
__global__ __launch_bounds__(256) void hist_kernel(
    const int* __restrict__ ei, const int* __restrict__ cluster1,
    const int* __restrict__ cluster2,
    int* __restrict__ deg, int* __restrict__ rank,
    int* __restrict__ cdeg, int* __restrict__ rankC,
    int* __restrict__ c2deg, int* __restrict__ rank2,
    int E, int N, int N1)
{
    int i = blockIdx.x * 256 + threadIdx.x;
    if (i < E)  rank[i]  = atomicAdd(&deg[ei[E + i]], 1);
    if (i < N)  rankC[i] = atomicAdd(&cdeg[cluster1[i]], 1);
    if (i < N1) rank2[i] = atomicAdd(&c2deg[cluster2[i]], 1);
}

// ---- phase 2: single-pass exclusive scan, 3 arrays in one launch. ----
#define SCAN_CHUNK 4096

__global__ __launch_bounds__(256) void scan_one(
    const int* __restrict__ in0, int* __restrict__ out0, int* __restrict__ st0, int L0, int nb0,
    const int* __restrict__ in1, int* __restrict__ out1, int* __restrict__ st1, int L1, int nb1,
    const int* __restrict__ in2, int* __restrict__ out2, int* __restrict__ st2, int L2)
{
    int b = blockIdx.x;
    const int* in; int* out; int* st; int L;
    if (b < nb0)            { in = in0; out = out0; st = st0; L = L0; }
    else if (b < nb0 + nb1) { b -= nb0; in = in1; out = out1; st = st1; L = L1; }
    else                    { b -= nb0 + nb1; in = in2; out = out2; st = st2; L = L2; }
    int nb = (L + SCAN_CHUNK - 1) / SCAN_CHUNK;

    __shared__ int ls[256];
    __shared__ int pre[32];
    __shared__ int blkExcl;
    int t = threadIdx.x;
    int base = b * SCAN_CHUNK + t * 16;
    int v[16];
    int s = 0;
#pragma unroll
    for (int j = 0; j < 16; ++j) {
        int val = (base + j < L) ? in[base + j] : 0;
        v[j] = s;
        s += val;
    }
    ls[t] = s;
    __syncthreads();
    for (int off = 1; off < 256; off <<= 1) {
        int tv = (t >= off) ? ls[t - off] : 0;
        __syncthreads();
        ls[t] += tv;
        __syncthreads();
    }
    int excl = ls[t] - s;
    int total = ls[255];
    if (t == 255) {
        __threadfence();
        atomicExch(&st[b], total + 1);   // publish early (before lookback)
    }
    if (t < b) {                          // b <= 19 < 32
        int val;
        do { val = atomicAdd(&st[t], 0); } while (val == 0);
        pre[t] = val - 1;
    }
    __syncthreads();
    if (t == 0) {
        int r = 0;
        for (int j = 0; j < b; ++j) r += pre[j];
        blkExcl = r;
    }
    __syncthreads();
    int be = blkExcl;
#pragma unroll
    for (int j = 0; j < 16; ++j)
        if (base + j < L) out[base + j] = be + excl + v[j];
    if (b == nb - 1 && t == 255) out[L] = be + total;
}

// ---- phase 3 (fused): CSR scatter + level-1 message compute. ----
__global__ __launch_bounds__(256) void scatB_kernel(
    const int* __restrict__ ei, const float* __restrict__ attr,
    const int* __restrict__ cluster1, const int* __restrict__ cluster2,
    const float2* __restrict__ x, const float* __restrict__ W1,
    const int* __restrict__ doffs, const int* __restrict__ rank,
    const int* __restrict__ coff, const int* __restrict__ rankC,
    const int* __restrict__ c2off, const int* __restrict__ rank2,
    int* __restrict__ nidx, int* __restrict__ n1idx,
    int4* __restrict__ rec4, int E, int N, int N1)
{
    __shared__ float lw[27 * W1_STRIDE];
    for (int i = threadIdx.x; i < 27 * 16; i += 256)
        lw[(i >> 4) * W1_STRIDE + (i & 15)] = W1[i];
    __syncthreads();

    int i = blockIdx.x * 256 + threadIdx.x;
    if (i < E) {
        int s = ei[i], d = ei[E + i];
        int p = doffs[d] + rank[i];

        float vx = attr[3 * i] * 2.f, vy = attr[3 * i + 1] * 2.f, vz = attr[3 * i + 2] * 2.f;
        float ix = fmaxf(fminf(floorf(vx), 1.f), 0.f);
        float iy = fmaxf(fminf(floorf(vy), 1.f), 0.f);
        float iz = fmaxf(fminf(floorf(vz), 1.f), 0.f);
        float fx = vx - ix, fy = vy - iy, fz = vz - iz;
        int ibase = (int)ix + 3 * (int)iy + 9 * (int)iz;

        float2 xv = x[s];  // 640 KB, L2-resident random read
        float wxv[2] = {1.f - fx, fx}, wyv[2] = {1.f - fy, fy}, wzv[2] = {1.f - fz, fz};
        float m[8];
#pragma unroll
        for (int o = 0; o < 8; ++o) m[o] = 0.f;
#pragma unroll
        for (int j = 0; j < 8; ++j) {
            int cx = j & 1, cy = (j >> 1) & 1, cz = j >> 2;
            float w = wxv[cx] * wyv[cy] * wzv[cz];
            const float* Wk = &lw[(ibase + cx + 3 * cy + 9 * cz) * W1_STRIDE];
            float a = w * xv.x, bb = w * xv.y;
            const float4 wa0 = *(const float4*)&Wk[0];
            const float4 wa1 = *(const float4*)&Wk[4];
            const float4 wb0 = *(const float4*)&Wk[8];
            const float4 wb1 = *(const float4*)&Wk[12];
            m[0] += a * wa0.x + bb * wb0.x;
            m[1] += a * wa0.y + bb * wb0.y;
            m[2] += a * wa0.z + bb * wb0.z;
            m[3] += a * wa0.w + bb * wb0.w;
            m[4] += a * wa1.x + bb * wb1.x;
            m[5] += a * wa1.y + bb * wb1.y;
            m[6] += a * wa1.z + bb * wb1.z;
            m[7] += a * wa1.w + bb * wb1.w;
        }

        unsigned hfx = __half_as_ushort(__float2half_rn(fx));
        unsigned hfy = __half_as_ushort(__float2half_rn(fy));
        unsigned hfz = __half_as_ushort(__float2half_rn(fz));
        int s2 = cluster1[s];
        int4 ra = make_int4(s2 | (ibase << 16),
                            (int)(hfx | (hfy << 16)), (int)hfz, d);
        __half2 h01 = __floats2half2_rn(m[0], m[1]);
        __half2 h23 = __floats2half2_rn(m[2], m[3]);
        __half2 h45 = __floats2half2_rn(m[4], m[5]);
        __half2 h67 = __floats2half2_rn(m[6], m[7]);
        int4 rb = make_int4(*(int*)&h01, *(int*)&h23, *(int*)&h45, *(int*)&h67);
        rec4[2 * (size_t)p]     = ra;
        rec4[2 * (size_t)p + 1] = rb;
    }
    if (i < N)  nidx[coff[cluster1[i]] + rankC[i]] = i;
    if (i < N1) n1idx[c2off[cluster2[i]] + rank2[i]] = i;
}

// ---- level-1 reduce: WAVE per node, WIDE loads (uint2/lane, 32 slots). ----
__global__ __launch_bounds__(256) void reduce1_kernel(
    const int* __restrict__ doffs, const unsigned short* __restrict__ recU,
    float* __restrict__ M1, int N)
{
    int lane = threadIdx.x & 63;
    int part = lane & 1;            // 0: ch0-3, 1: ch4-7
    int d = (blockIdx.x << 2) + (threadIdx.x >> 6);
    if (d >= N) return;
    int beg = doffs[d], end = doffs[d + 1];
    float a0 = 0.f, a1 = 0.f, a2 = 0.f, a3 = 0.f;
    for (int p0 = beg; p0 < end; p0 += 32) {
        int s = p0 + (lane >> 1);
        if (s < end) {
            uint2 u = *(const uint2*)&recU[(size_t)s * 16 + 8 + part * 4];
            a0 += hlou(u.x); a1 += hhiu(u.x);
            a2 += hlou(u.y); a3 += hhiu(u.y);
        }
    }
#pragma unroll
    for (int m = 2; m <= 32; m <<= 1) {
        a0 += __shfl_xor(a0, m);
        a1 += __shfl_xor(a1, m);
        a2 += __shfl_xor(a2, m);
        a3 += __shfl_xor(a3, m);
    }
    float inv = 1.f / fmaxf((float)(end - beg), 1.f);
    if (lane < 2)
        *(float4*)&M1[(size_t)d * 8 + part * 4] =
            make_float4(a0 * inv, a1 * inv, a2 * inv, a3 * inv);
}

// ---- level 1 pool: per (cluster, ch); emits x1c (f32) + x1ch (half) ----
__global__ __launch_bounds__(256) void node1_kernel(
    const int* __restrict__ coff, const int* __restrict__ nidx,
    const float* __restrict__ M1, const float2* __restrict__ x,
    const float* __restrict__ root1, const float* __restrict__ b1,
    const int* __restrict__ batch,
    float* __restrict__ x1c, unsigned short* __restrict__ x1chU,
    int* __restrict__ batch1, int N1)
{
    int t = blockIdx.x * 256 + threadIdx.x;
    if (t >= N1 * 8) return;
    int c = t >> 3, ch = t & 7;
    int cb = coff[c], ce = coff[c + 1];
    float r0 = root1[ch], r1 = root1[8 + ch], bo = b1[ch];
    float hm = -INFINITY;
    int bm = 0;
    for (int idx = cb; idx < ce; ++idx) {
        int d = nidx[idx];
        float2 xv = x[d];
        float h = eluf(M1[d * 8 + ch] + xv.x * r0 + xv.y * r1 + bo);
        hm = fmaxf(hm, h);
        bm = max(bm, batch[d]);
    }
    if (ce == cb) hm = 0.f;  // empty cluster -> 0 (ref isfinite mask)
    x1c[t] = hm;
    x1chU[t] = __half_as_ushort(__float2half_rn(hm));
    if (ch == 0) batch1[c] = bm;
}

// ---- level 2 edge blend: block=1024 (256 edges x 4 oq). Counting-sort
//      the block's edges by ibase (8 distinct values) so each wave's 16
//      edge-slots share the k-row -> W2 b128 reads become broadcasts.
//      R0 LDS data layout retained. ----
__global__ __launch_bounds__(1024) void edge2m_kernel(
    const int4* __restrict__ rec4, const unsigned short* __restrict__ x1chU,
    const float* __restrict__ W2, unsigned short* __restrict__ msg2h, int E)
{
    __shared__ unsigned lwh[27 * W2H_STRIDE];
    __shared__ int bcnt[16];
    __shared__ int boff[16];
    __shared__ short sidx[256];
    int tid = threadIdx.x;
    for (int i = tid; i < 27 * 64; i += 1024) {
        int k = i >> 6, r = i & 63;      // r = o*4 + c2
        int o = r >> 2, c2 = r & 3;
        float a = W2[(k * 8 + 2 * c2) * 16 + o];
        float b = W2[(k * 8 + 2 * c2 + 1) * 16 + o];
        __half2 h = __floats2half2_rn(a, b);
        lwh[k * W2H_STRIDE + r] = *(unsigned*)&h;
    }
    if (tid < 16) bcnt[tid] = 0;
    __syncthreads();

    int base = blockIdx.x * 256;
    int nE = E - base; if (nE > 256) nE = 256;
    int key = 0, rnk = 0;
    if (tid < nE) {
        key = (((const int*)rec4)[(size_t)(base + tid) * 8] >> 16) & 15;  // ibase in {0,1,3,4,9,10,12,13}
        rnk = atomicAdd(&bcnt[key], 1);
    }
    __syncthreads();
    if (tid == 0) {
        int r = 0;
        for (int j = 0; j < 16; ++j) { boff[j] = r; r += bcnt[j]; }
    }
    __syncthreads();
    if (tid < nE) sidx[boff[key] + rnk] = (short)tid;
    __syncthreads();

    int es = tid >> 2;                   // sorted edge slot
    if (es >= nE) return;                // all barriers done
    int oq = tid & 3;                    // outputs o0..o0+3, o0 = oq*4
    int p = base + sidx[es];
    int4 m = rec4[2 * (size_t)p];        // 4 threads broadcast-load same 16 B
    int s2 = m.x & 0xFFFF;
    int ibase = (m.x >> 16) & 31;
    float fx = hlo(m.y), fy = hhi(m.y), fz = hlo(m.z);

    const uint4 xv4 = *(const uint4*)&x1chU[(size_t)s2 * 8];
    half2v xh0 = uash2(xv4.x), xh1 = uash2(xv4.y),
           xh2 = uash2(xv4.z), xh3 = uash2(xv4.w);

    float wx0 = 1.f - fx, wy0 = 1.f - fy, wz0 = 1.f - fz;
    float acc0 = 0.f, acc1 = 0.f, acc2 = 0.f, acc3 = 0.f;
#pragma unroll
    for (int j = 0; j < 8; ++j) {
        int cx = j & 1, cy = (j >> 1) & 1, cz = j >> 2;
        float w = (cx ? fx : wx0) * (cy ? fy : wy0) * (cz ? fz : wz0);
        int k = ibase + cx + 3 * cy + 9 * cz;
        const unsigned* bptr = &lwh[k * W2H_STRIDE + oq * 16];
        uint4 v0 = *(const uint4*)(bptr);
        uint4 v1 = *(const uint4*)(bptr + 4);
        uint4 v2 = *(const uint4*)(bptr + 8);
        uint4 v3 = *(const uint4*)(bptr + 12);
        float s0 = dot2f(xh0, uash2(v0.x), dot2f(xh1, uash2(v0.y),
                   dot2f(xh2, uash2(v0.z), dot2f(xh3, uash2(v0.w), 0.f))));
        float s1 = dot2f(xh0, uash2(v1.x), dot2f(xh1, uash2(v1.y),
                   dot2f(xh2, uash2(v1.z), dot2f(xh3, uash2(v1.w), 0.f))));
        float s2v = dot2f(xh0, uash2(v2.x), dot2f(xh1, uash2(v2.y),
                    dot2f(xh2, uash2(v2.z), dot2f(xh3, uash2(v2.w), 0.f))));
        float s3 = dot2f(xh0, uash2(v3.x), dot2f(xh1, uash2(v3.y),
                   dot2f(xh2, uash2(v3.z), dot2f(xh3, uash2(v3.w), 0.f))));
        acc0 = fmaf(w, s0, acc0);
        acc1 = fmaf(w, s1, acc1);
        acc2 = fmaf(w, s2v, acc2);
        acc3 = fmaf(w, s3, acc3);
    }
    __half2 lo = __floats2half2_rn(acc0, acc1);
    __half2 hi = __floats2half2_rn(acc2, acc3);
    uint2 outv = make_uint2(*(unsigned*)&lo, *(unsigned*)&hi);
    *(uint2*)&msg2h[(size_t)p * 16 + oq * 4] = outv;  // window-scattered, L2-absorbed
}

// ---- level 2 reduce: WAVE per cluster, WIDE loads (uint/lane, 8 slots). ----
__global__ __launch_bounds__(256) void reduce2_kernel(
    const int* __restrict__ coff, const int* __restrict__ nidx,
    const int* __restrict__ doffs, const unsigned short* __restrict__ msg2h,
    float* __restrict__ M2, int N1)
{
    int lane = threadIdx.x & 63;
    int opos = lane & 7;            // o-pair: o = 2*opos, 2*opos+1
    int c = (blockIdx.x << 2) + (threadIdx.x >> 6);
    if (c >= N1) return;
    int cb = coff[c], ce = coff[c + 1];
    float a0 = 0.f, a1 = 0.f;
    int cnt = 0;
    for (int idx = cb; idx < ce; ++idx) {
        int d = nidx[idx];
        int beg = doffs[d], end = doffs[d + 1];
        cnt += end - beg;
        for (int p0 = beg; p0 < end; p0 += 8) {
            int s = p0 + (lane >> 3);
            if (s < end) {
                unsigned u = *(const unsigned*)&msg2h[(size_t)s * 16 + opos * 2];
                a0 += hlou(u); a1 += hhiu(u);
            }
        }
    }
#pragma unroll
    for (int m = 8; m <= 32; m <<= 1) {
        a0 += __shfl_xor(a0, m);
        a1 += __shfl_xor(a1, m);
    }
    float inv = 1.f / fmaxf((float)cnt, 1.f);
    if (lane < 8)
        *(float2*)&M2[(size_t)c * 16 + opos * 2] = make_float2(a0 * inv, a1 * inv);
}

// ---- level 2 node + pool + graph sum (LDS-binned; tiny atomic tail) ----
__global__ __launch_bounds__(256) void node2_kernel(
    const int* __restrict__ c2off, const int* __restrict__ n1idx,
    const float* __restrict__ M2, const float* __restrict__ x1c,
    const float* __restrict__ root2, const float* __restrict__ b2,
    const int* __restrict__ batch1,
    float* __restrict__ gsum, float* __restrict__ gcnt, int N2)
{
    __shared__ float ls[16 * 16];
    __shared__ float lc[16];
    for (int i = threadIdx.x; i < 256; i += 256) ls[i] = 0.f;
    if (threadIdx.x < 16) lc[threadIdx.x] = 0.f;
    __syncthreads();

    int c2 = blockIdx.x * 256 + threadIdx.x;
    if (c2 < N2) {
        int cb = c2off[c2], ce = c2off[c2 + 1];
        float hm[16];
#pragma unroll
        for (int o = 0; o < 16; ++o) hm[o] = -INFINITY;
        int bm = 0;
        for (int idx = cb; idx < ce; ++idx) {
            int n1 = n1idx[idx];
            const float4* xr4 = (const float4*)&x1c[(size_t)n1 * 8];
            float4 xa = xr4[0], xb = xr4[1];
            float xr[8] = {xa.x, xa.y, xa.z, xa.w, xb.x, xb.y, xb.z, xb.w};
#pragma unroll
            for (int o = 0; o < 16; ++o) {
                float v = M2[(size_t)n1 * 16 + o] + b2[o];
#pragma unroll
                for (int c8 = 0; c8 < 8; ++c8) v += xr[c8] * root2[c8 * 16 + o];
                hm[o] = fmaxf(hm[o], eluf(v));
            }
            bm = max(bm, batch1[n1]);
        }
        if (ce == cb) {
#pragma unroll
            for (int o = 0; o < 16; ++o) hm[o] = 0.f;
        }
#pragma unroll
        for (int o = 0; o < 16; ++o) atomicAdd(&ls[bm * 16 + o], hm[o]);
        atomicAdd(&lc[bm], 1.f);
    }
    __syncthreads();
    for (int i = threadIdx.x; i < 256; i += 256) unsafeAtomicAdd(&gsum[i], ls[i]);
    if (threadIdx.x < 16) unsafeAtomicAdd(&gcnt[threadIdx.x], lc[threadIdx.x]);
}

// ---- head ----
__global__ __launch_bounds__(256) void head_kernel(
    const float* __restrict__ gsum, const float* __restrict__ gcnt,
    const float* __restrict__ fc1_w, const float* __restrict__ fc1_b,
    const float* __restrict__ fc2_w, const float* __restrict__ fc2_b,
    float* __restrict__ out, int B)
{
    __shared__ float g[16 * 16];
    __shared__ float h1[16 * 64];
    int t = threadIdx.x;
    if (t < B * 16) {
        int b = t >> 4;
        g[t] = gsum[t] / fmaxf(gcnt[b], 1.f);
    }
    __syncthreads();
    for (int j = t; j < B * 64; j += 256) {
        int b = j >> 6, jj = j & 63;
        float s = fc1_b[jj];
#pragma unroll
        for (int c = 0; c < 16; ++c) s += g[b * 16 + c] * fc1_w[c * 64 + jj];
        h1[j] = eluf(s);
    }
    __syncthreads();
    if (t < B) {
        float s = fc2_b[0];
#pragma unroll
        for (int j = 0; j < 64; ++j) s += h1[t * 64 + j] * fc2_w[j];
        out[t] = eluf(s);
    }
}

extern "C" void kernel_launch(void* const* d_in, const int* in_sizes, int n_in,
                              void* d_out, int out_size, void* d_ws, size_t ws_size,
                              hipStream_t stream)
{
    const float* x        = (const float*)d_in[0];
    const int*   ei       = (const int*)  d_in[1];
    const float* attr     = (const float*)d_in[2];
    const int*   batch    = (const int*)  d_in[3];
    const int*   cluster1 = (const int*)  d_in[4];
    const int*   cluster2 = (const int*)  d_in[5];
    const float* W1       = (const float*)d_in[6];
    const float* root1    = (const float*)d_in[7];
    const float* b1       = (const float*)d_in[8];
    const float* W2       = (const float*)d_in[9];
    const float* root2    = (const float*)d_in[10];
    const float* b2       = (const float*)d_in[11];
    const float* fc1_w    = (const float*)d_in[12];
    const float* fc1_b    = (const float*)d_in[13];
    const float* fc2_w    = (const float*)d_in[14];
    const float* fc2_b    = (const float*)d_in[15];

    const int N  = in_sizes[0] / 2;
    const int E  = in_sizes[1] / 2;
    const int N1 = in_sizes[5];
    const int N2 = N1 / 2;
    const int B  = out_size;

    const int nb0 = (N  + SCAN_CHUNK - 1) / SCAN_CHUNK;
    const int nb1 = (N1 + SCAN_CHUNK - 1) / SCAN_CHUNK;
    const int nb2 = (N2 + SCAN_CHUNK - 1) / SCAN_CHUNK;

    int* wi = (int*)d_ws;
    size_t off = 0;
    auto alloc = [&](size_t n, size_t align = 1) {
        off = (off + align - 1) & ~(align - 1);
        size_t r = off; off += n; return r;
    };
    // zero-init region
    int*   deg    = wi + alloc(N);
    int*   cdeg   = wi + alloc(N1);
    int*   c2deg  = wi + alloc(N2);
    float* gsum   = (float*)(wi + alloc((size_t)B * 16));
    float* gcnt   = (float*)(wi + alloc(B));
    int*   st0    = wi + alloc(32);
    int*   st1    = wi + alloc(32);
    int*   st2    = wi + alloc(32);
    const size_t zcount = off;
    // rest (fully overwritten before read)
    int*   doffs  = wi + alloc(N + 1);
    int*   coff   = wi + alloc(N1 + 1);
    int*   c2off  = wi + alloc(N2 + 1);
    int*   rank   = wi + alloc(E);
    int*   rankC  = wi + alloc(N);
    int*   rank2  = wi + alloc(N1);
    int*   nidx   = wi + alloc(N);
    int*   n1idx  = wi + alloc(N1);
    int4*  rec4   = (int4*)(wi + alloc((size_t)E * 8, 8));   // 32-B records
    unsigned short* msg2h = (unsigned short*)(wi + alloc((size_t)E * 8, 4));
    float* M1     = (float*)(wi + alloc((size_t)N * 8, 4));
    float* x1c    = (float*)(wi + alloc((size_t)N1 * 8, 4));
    unsigned short* x1chU = (unsigned short*)(wi + alloc((size_t)N1 * 4, 4));
    int*   batch1 = wi + alloc(N1);
    float* M2     = (float*)(wi + alloc((size_t)N1 * 16, 4));
    (void)ws_size;  // peak ~96 MB (R5-proven capacity ~113 MB)

    hipMemsetAsync(d_ws, 0, zcount * sizeof(int), stream);

    const int eb = (E + 255) / 256;
    hist_kernel<<<eb, 256, 0, stream>>>(ei, cluster1, cluster2,
                                        deg, rank, cdeg, rankC, c2deg, rank2, E, N, N1);
    scan_one<<<nb0 + nb1 + nb2, 256, 0, stream>>>(deg, doffs, st0, N, nb0,
                                                  cdeg, coff, st1, N1, nb1,
                                                  c2deg, c2off, st2, N2);
    scatB_kernel<<<eb, 256, 0, stream>>>(ei, attr, cluster1, cluster2,
                                         (const float2*)x, W1,
                                         doffs, rank, coff, rankC, c2off, rank2,
                                         nidx, n1idx, rec4, E, N, N1);
    reduce1_kernel<<<(N + 3) / 4, 256, 0, stream>>>(
        doffs, (const unsigned short*)rec4, M1, N);
    node1_kernel<<<(N1 * 8 + 255) / 256, 256, 0, stream>>>(
        coff, nidx, M1, (const float2*)x, root1, b1, batch,
        x1c, x1chU, batch1, N1);
    edge2m_kernel<<<(E + 255) / 256, 1024, 0, stream>>>(
        rec4, x1chU, W2, msg2h, E);
    reduce2_kernel<<<(N1 + 3) / 4, 256, 0, stream>>>(
        coff, nidx, doffs, msg2h, M2, N1);
    node2_kernel<<<(N2 + 255) / 256, 256, 0, stream>>>(
        c2off, n1idx, M2, x1c, root2, b2, batch1, gsum, gcnt, N2);
    head_kernel<<<1, 256, 0, stream>>>(gsum, gcnt, fc1_w, fc1_b, fc2_w, fc2_b,
                                       (float*)d_out, B);
}